// Round 3
// baseline (21056.062 us; speedup 1.0000x reference)
//
#include <hip/hip_runtime.h>

#define N_NODES 131072
#define N_EDGES 524288
#define CCH 256
#define N_GRAPHS_ 2048
#define SEQ 64
#define LAYERS 6

typedef unsigned short US;

__device__ __forceinline__ float b2f(US u) { return __uint_as_float(((unsigned)u) << 16); }
__device__ __forceinline__ US f2b(float f) {
    unsigned u = __float_as_uint(f);
    return (US)((u + 0x7fff + ((u >> 16) & 1)) >> 16);   // RNE
}

// small cross-kernel state (zero-init .bss; stats re-zeroed after each use)
__device__ float g_stats[512];
__device__ float g_aff1[512];
__device__ float g_aff2[512];
__device__ float g_aff3[512];
__device__ float g_peaff[40];

// ---------------------------------------------------------------- pe stats
__global__ __launch_bounds__(256) void pe_stats_k(const float* __restrict__ pe,
                                                  const float* __restrict__ g,
                                                  const float* __restrict__ b) {
    __shared__ float sbuf[256], s2buf[256];
    int ch = blockIdx.x;   // 0..19
    int tid = threadIdx.x;
    float s = 0.f, s2 = 0.f;
    for (int i = tid; i < N_NODES; i += 256) {
        float v = pe[(size_t)i * 20 + ch];
        s += v; s2 += v * v;
    }
    sbuf[tid] = s; s2buf[tid] = s2;
    __syncthreads();
    for (int off = 128; off; off >>= 1) {
        if (tid < off) { sbuf[tid] += sbuf[tid + off]; s2buf[tid] += s2buf[tid + off]; }
        __syncthreads();
    }
    if (tid == 0) {
        float mean = sbuf[0] / (float)N_NODES;
        float var  = s2buf[0] / (float)N_NODES - mean * mean;
        float a = g[ch] * rsqrtf(var + 1e-5f);
        g_peaff[ch] = a;
        g_peaff[20 + ch] = b[ch] - mean * a;
    }
}

// ---------------------------------------------------------------- embed
__global__ __launch_bounds__(256) void embed_k(const int* __restrict__ x,
                                               const float* __restrict__ pe,
                                               const float* __restrict__ node_emb,
                                               const float* __restrict__ plw,
                                               const float* __restrict__ plb,
                                               US* __restrict__ h) {
    int n = blockIdx.x;
    int tid = threadIdx.x;
    int xi = x[n];
    float v;
    if (tid < 192) {
        v = node_emb[xi * 192 + tid];
    } else {
        int j = tid - 192;
        float s = plb[j];
        #pragma unroll
        for (int k = 0; k < 20; k++) {
            float p = pe[(size_t)n * 20 + k] * g_peaff[k] + g_peaff[20 + k];
            s += p * plw[k * 64 + j];
        }
        v = s;
    }
    h[(size_t)n * CCH + tid] = f2b(v);
}

// ---------------------------------------------------------------- edge aggregation (per graph, LDS)
// z = h + sum_{e: dst} relu(h[src] + eemb[attr]); edges of graph g are e in [g*256,(g+1)*256)
__global__ __launch_bounds__(256) void aggr_z_k(const US* __restrict__ h,
                                                const int* __restrict__ ei,
                                                const int* __restrict__ attr,
                                                const float* __restrict__ eemb,
                                                US* __restrict__ z) {
    __shared__ float zt[64][129];
    int g = blockIdx.x;
    int c0 = blockIdx.y * 128;
    int tid = threadIdx.x;
    for (int i = tid; i < 64 * 128; i += 256) {
        int r = i >> 7, c = i & 127;
        zt[r][c] = b2f(h[(size_t)(g * 64 + r) * CCH + c0 + c]);
    }
    __syncthreads();
    int esub = tid >> 7;        // 0..1
    int col = tid & 127;
    for (int it = 0; it < 128; it++) {
        int e = g * 256 + it * 2 + esub;
        int src = ei[e];
        int dst = ei[N_EDGES + e];
        int a = attr[e];
        float v = b2f(h[(size_t)src * CCH + c0 + col]) + eemb[a * CCH + c0 + col];
        v = fmaxf(v, 0.f);
        atomicAdd(&zt[dst - g * 64][col], v);
    }
    __syncthreads();
    for (int i = tid; i < 64 * 128; i += 256) {
        int r = i >> 7, c = i & 127;
        z[(size_t)(g * 64 + r) * CCH + c0 + c] = f2b(zt[r][c]);
    }
}

// ---------------------------------------------------------------- bf16-storage f32-math GEMM
// Y[r,col0+c] = A[M,256]@W[:,cols] + bias ; ldY=ldA=ldres=256 fixed, K=256 fixed.
// mode 0: none, 1: relu, 2: += res
__global__ __launch_bounds__(256) void gemm_k(const US* __restrict__ A,
                                              const float* __restrict__ W, int ldw,
                                              const float* __restrict__ bias,
                                              const US* __restrict__ res,
                                              US* __restrict__ Y, int mode) {
    __shared__ float As[16][68];
    __shared__ float Bs[16][64];
    int tid = threadIdx.x;
    int row0 = blockIdx.x * 64;
    int col0 = blockIdx.y * 64;
    int tx = tid & 15, ty = tid >> 4;
    int la_r = tid >> 2;
    int la_k = (tid & 3) * 4;
    int lb_k = tid >> 4;
    int lb_n = (tid & 15) * 4;
    float acc[4][4] = {};
    for (int k0 = 0; k0 < 256; k0 += 16) {
        ushort4 a4 = *(const ushort4*)(A + (size_t)(row0 + la_r) * 256 + k0 + la_k);
        As[la_k + 0][la_r] = b2f(a4.x);
        As[la_k + 1][la_r] = b2f(a4.y);
        As[la_k + 2][la_r] = b2f(a4.z);
        As[la_k + 3][la_r] = b2f(a4.w);
        float4 b4 = *(const float4*)(W + (size_t)(k0 + lb_k) * ldw + col0 + lb_n);
        *(float4*)&Bs[lb_k][lb_n] = b4;
        __syncthreads();
        #pragma unroll
        for (int kk = 0; kk < 16; kk++) {
            float av[4], bv[4];
            #pragma unroll
            for (int i = 0; i < 4; i++) av[i] = As[kk][ty * 4 + i];
            #pragma unroll
            for (int j = 0; j < 4; j++) bv[j] = Bs[kk][tx * 4 + j];
            #pragma unroll
            for (int i = 0; i < 4; i++)
                #pragma unroll
                for (int j = 0; j < 4; j++)
                    acc[i][j] += av[i] * bv[j];
        }
        __syncthreads();
    }
    #pragma unroll
    for (int i = 0; i < 4; i++) {
        int r = row0 + ty * 4 + i;
        int c = col0 + tx * 4;
        float v[4];
        #pragma unroll
        for (int j = 0; j < 4; j++) {
            v[j] = acc[i][j] + (bias ? bias[c + j] : 0.f);
            if (mode == 1) v[j] = fmaxf(v[j], 0.f);
        }
        if (mode == 2) {
            ushort4 r4 = *(const ushort4*)(res + (size_t)r * 256 + c);
            v[0] += b2f(r4.x); v[1] += b2f(r4.y); v[2] += b2f(r4.z); v[3] += b2f(r4.w);
        }
        ushort4 yv;
        yv.x = f2b(v[0]); yv.y = f2b(v[1]); yv.z = f2b(v[2]); yv.w = f2b(v[3]);
        *(ushort4*)(Y + (size_t)r * 256 + c) = yv;
    }
}

// ---------------------------------------------------------------- per-graph attention (one head)
// qkv packed in A: q cols 0..63, k cols 64..127, v cols 128..191 (ld 256, bf16)
// writes o (pre-offset to head's column block, ld 256, bf16)
__global__ __launch_bounds__(256) void attn_k(const US* __restrict__ qkv,
                                              US* __restrict__ o) {
    __shared__ float Qs[64][68], Ks[64][68], Vs[64][68];
    int g = blockIdx.x, tid = threadIdx.x;
    int r = tid >> 2;          // row 0..63
    int cg = tid & 3;          // col group
    int cb = cg * 16;
    const US* base = qkv + (size_t)(g * 64 + r) * 256 + cb;
    #pragma unroll
    for (int i = 0; i < 16; i++) {
        Qs[r][cb + i] = b2f(base[i]);
        Ks[r][cb + i] = b2f(base[64 + i]);
        Vs[r][cb + i] = b2f(base[128 + i]);
    }
    __syncthreads();
    float s[16];
    #pragma unroll
    for (int m = 0; m < 16; m++) s[m] = 0.f;
    for (int kk = 0; kk < 64; kk++) {
        float qv = Qs[r][kk];
        #pragma unroll
        for (int m = 0; m < 16; m++)
            s[m] += qv * Ks[cg + 4 * m][kk];
    }
    float mx = -1e30f;
    #pragma unroll
    for (int m = 0; m < 16; m++) { s[m] *= 0.125f; mx = fmaxf(mx, s[m]); }
    mx = fmaxf(mx, __shfl_xor(mx, 1));
    mx = fmaxf(mx, __shfl_xor(mx, 2));
    float sum = 0.f;
    #pragma unroll
    for (int m = 0; m < 16; m++) { s[m] = __expf(s[m] - mx); sum += s[m]; }
    sum += __shfl_xor(sum, 1);
    sum += __shfl_xor(sum, 2);
    float inv = 1.f / sum;
    __syncthreads();                 // Qs dead -> reuse as P
    #pragma unroll
    for (int m = 0; m < 16; m++) Qs[r][cg + 4 * m] = s[m] * inv;
    __syncthreads();
    float acc[16];
    #pragma unroll
    for (int m = 0; m < 16; m++) acc[m] = 0.f;
    for (int kk = 0; kk < 64; kk++) {
        float pv = Qs[r][kk];
        #pragma unroll
        for (int m = 0; m < 16; m++)
            acc[m] += pv * Vs[kk][cg + 4 * m];
    }
    US* ob = o + (size_t)(g * 64 + r) * 256;
    #pragma unroll
    for (int m = 0; m < 16; m++) ob[cg + 4 * m] = f2b(acc[m]);
}

// ---------------------------------------------------------------- BN stats / affine
__global__ __launch_bounds__(256) void stats_k(const US* __restrict__ Y) {
    int c = threadIdx.x;
    size_t r0 = (size_t)blockIdx.x * 128;
    float s = 0.f, s2 = 0.f;
    for (int r = 0; r < 128; r++) {
        float v = b2f(Y[(r0 + r) * CCH + c]);
        s += v; s2 += v * v;
    }
    atomicAdd(&g_stats[c], s);
    atomicAdd(&g_stats[CCH + c], s2);
}

__global__ __launch_bounds__(256) void affine_k(const float* __restrict__ g,
                                                const float* __restrict__ b, int sel) {
    int c = threadIdx.x;
    float mean = g_stats[c] / (float)N_NODES;
    float var  = g_stats[CCH + c] / (float)N_NODES - mean * mean;
    float a = g[c] * rsqrtf(var + 1e-5f);
    float* dst = (sel == 0) ? g_aff1 : (sel == 1) ? g_aff2 : g_aff3;
    dst[c] = a;
    dst[CCH + c] = b[c] - mean * a;
    g_stats[c] = 0.f;          // re-zero for next stats pass (deterministic invariant)
    g_stats[CCH + c] = 0.f;
}

// ---------------------------------------------------------------- elementwise
__global__ __launch_bounds__(256) void combine_k(const US* __restrict__ y1,
                                                 const US* __restrict__ y2,
                                                 US* __restrict__ out) {
    size_t i = (size_t)blockIdx.x * 256 + threadIdx.x;
    size_t stride = (size_t)gridDim.x * 256;
    for (; i < (size_t)N_NODES * CCH; i += stride) {
        int c = (int)(i & 255);
        float v = (b2f(y1[i]) * g_aff1[c] + g_aff1[CCH + c]) +
                  (b2f(y2[i]) * g_aff2[c] + g_aff2[CCH + c]);
        out[i] = f2b(v);
    }
}

__global__ __launch_bounds__(256) void apply_k(US* __restrict__ h) {
    size_t i = (size_t)blockIdx.x * 256 + threadIdx.x;
    size_t stride = (size_t)gridDim.x * 256;
    for (; i < (size_t)N_NODES * CCH; i += stride) {
        int c = (int)(i & 255);
        h[i] = f2b(b2f(h[i]) * g_aff3[c] + g_aff3[CCH + c]);
    }
}

// ---------------------------------------------------------------- pool + head
__global__ __launch_bounds__(256) void pool_k(const US* __restrict__ h,
                                              float* __restrict__ pooled) {
    int g = blockIdx.x, c = threadIdx.x;
    float s = 0.f;
    for (int ss = 0; ss < SEQ; ss++) s += b2f(h[((size_t)g * SEQ + ss) * CCH + c]);
    pooled[(size_t)g * CCH + c] = s;
}

__global__ __launch_bounds__(128) void head_k(const float* __restrict__ pooled,
                                              const float* __restrict__ w1, const float* __restrict__ b1,
                                              const float* __restrict__ w2, const float* __restrict__ b2,
                                              const float* __restrict__ w3, const float* __restrict__ b3,
                                              float* __restrict__ outp) {
    __shared__ float p[256], t1[128], t2[64];
    int g = blockIdx.x, tid = threadIdx.x;
    p[tid] = pooled[(size_t)g * CCH + tid];
    p[tid + 128] = pooled[(size_t)g * CCH + 128 + tid];
    __syncthreads();
    float s = b1[tid];
    for (int k = 0; k < 256; k++) s += p[k] * w1[k * 128 + tid];
    t1[tid] = fmaxf(s, 0.f);
    __syncthreads();
    if (tid < 64) {
        float s2 = b2[tid];
        for (int k = 0; k < 128; k++) s2 += t1[k] * w2[k * 64 + tid];
        t2[tid] = fmaxf(s2, 0.f);
    }
    __syncthreads();
    if (tid == 0) {
        float s3 = b3[0];
        for (int k = 0; k < 64; k++) s3 += t2[k] * w3[k];
        outp[g] = s3;
    }
}

// ================================================================ launch
extern "C" void kernel_launch(void* const* d_in, const int* in_sizes, int n_in,
                              void* d_out, int out_size, void* d_ws, size_t ws_size,
                              hipStream_t stream) {
    const int*   x         = (const int*)  d_in[0];
    const float* pe        = (const float*)d_in[1];
    const int*   ei        = (const int*)  d_in[2];
    const int*   eattr     = (const int*)  d_in[3];
    const float* node_emb  = (const float*)d_in[5];
    const float* pe_lin_w  = (const float*)d_in[6];
    const float* pe_lin_b  = (const float*)d_in[7];
    const float* pe_norm_g = (const float*)d_in[8];
    const float* pe_norm_b = (const float*)d_in[9];
    const float* edge_emb  = (const float*)d_in[10];
    const float* conv_w1   = (const float*)d_in[11];
    const float* conv_b1   = (const float*)d_in[12];
    const float* conv_w2   = (const float*)d_in[13];
    const float* conv_b2   = (const float*)d_in[14];
    const float* attn_in_w = (const float*)d_in[15];
    const float* attn_in_b = (const float*)d_in[16];
    const float* attn_out_w= (const float*)d_in[17];
    const float* attn_out_b= (const float*)d_in[18];
    const float* bn1_g     = (const float*)d_in[19];
    const float* bn1_b     = (const float*)d_in[20];
    const float* bn2_g     = (const float*)d_in[21];
    const float* bn2_b     = (const float*)d_in[22];
    const float* bn3_g     = (const float*)d_in[23];
    const float* bn3_b     = (const float*)d_in[24];
    const float* mlp_w1    = (const float*)d_in[25];
    const float* mlp_b1    = (const float*)d_in[26];
    const float* mlp_w2    = (const float*)d_in[27];
    const float* mlp_b2    = (const float*)d_in[28];
    const float* head_w1   = (const float*)d_in[29];
    const float* head_b1   = (const float*)d_in[30];
    const float* head_w2   = (const float*)d_in[31];
    const float* head_b2   = (const float*)d_in[32];
    const float* head_w3   = (const float*)d_in[33];
    const float* head_b3   = (const float*)d_in[34];
    (void)in_sizes; (void)n_in; (void)out_size; (void)ws_size;

    // workspace: exactly 4 x 64 MB bf16 [N,256] buffers = 256 MB total
    char* ws = (char*)d_ws;
    US* h    = (US*)(ws);
    US* A    = (US*)(ws + 67108864ULL);
    US* B    = (US*)(ws + 134217728ULL);
    US* C    = (US*)(ws + 201326592ULL);
    float* pooled = (float*)(ws + 67108864ULL);   // reuses A (dead after layer loop)

    pe_stats_k<<<20, 256, 0, stream>>>(pe, pe_norm_g, pe_norm_b);
    embed_k<<<N_NODES, 256, 0, stream>>>(x, pe, node_emb, pe_lin_w, pe_lin_b, h);

    for (int l = 0; l < LAYERS; l++) {
        const float* cw1 = conv_w1 + (size_t)l * 65536;
        const float* cw2 = conv_w2 + (size_t)l * 65536;
        const float* aiw = attn_in_w + (size_t)l * 196608;
        const float* aib = attn_in_b + (size_t)l * 768;
        const float* aow = attn_out_w + (size_t)l * 65536;
        const float* mw1 = mlp_w1 + (size_t)l * 131072;
        const float* mb1 = mlp_b1 + (size_t)l * 512;
        const float* mw2 = mlp_w2 + (size_t)l * 131072;

        // ---- local GINEConv ----
        aggr_z_k<<<dim3(N_GRAPHS_, 2), 256, 0, stream>>>(h, ei, eattr, edge_emb, A); // z=A
        gemm_k<<<dim3(2048, 4), 256, 0, stream>>>(A, cw1, 256, conv_b1 + l * 256, nullptr, B, 1); // t1
        gemm_k<<<dim3(2048, 4), 256, 0, stream>>>(B, cw2, 256, conv_b2 + l * 256, h, C, 2);       // y1
        stats_k<<<1024, 256, 0, stream>>>(C);
        affine_k<<<1, 256, 0, stream>>>(bn1_g + l * 256, bn1_b + l * 256, 0);

        // ---- global attention (per head; qkv packed in A, o packed in B) ----
        for (int hh = 0; hh < 4; hh++) {
            gemm_k<<<dim3(2048, 1), 256, 0, stream>>>(h, aiw + hh * 64,       768,
                                                      aib + hh * 64,       nullptr, A,       0); // q
            gemm_k<<<dim3(2048, 1), 256, 0, stream>>>(h, aiw + 256 + hh * 64, 768,
                                                      aib + 256 + hh * 64, nullptr, A + 64,  0); // k
            gemm_k<<<dim3(2048, 1), 256, 0, stream>>>(h, aiw + 512 + hh * 64, 768,
                                                      aib + 512 + hh * 64, nullptr, A + 128, 0); // v
            attn_k<<<N_GRAPHS_, 256, 0, stream>>>(A, B + hh * 64);                               // o_hh
        }
        gemm_k<<<dim3(2048, 4), 256, 0, stream>>>(B, aow, 256, attn_out_b + l * 256, h, h, 2);   // y2 -> h
        stats_k<<<1024, 256, 0, stream>>>(h);
        affine_k<<<1, 256, 0, stream>>>(bn2_g + l * 256, bn2_b + l * 256, 1);

        // ---- combine + FFN (512-wide hidden split into two 256 halves) ----
        combine_k<<<2048, 256, 0, stream>>>(C, h, A);                                            // out=A
        gemm_k<<<dim3(2048, 4), 256, 0, stream>>>(A, mw1,       512, mb1,       nullptr, B, 1);  // tA
        gemm_k<<<dim3(2048, 4), 256, 0, stream>>>(B, mw2,       256, mlp_b2 + l * 256, A, C, 2); // partial
        gemm_k<<<dim3(2048, 4), 256, 0, stream>>>(A, mw1 + 256, 512, mb1 + 256, nullptr, B, 1);  // tB
        gemm_k<<<dim3(2048, 4), 256, 0, stream>>>(B, mw2 + 65536, 256, nullptr, C, h, 2);        // y3 -> h
        stats_k<<<1024, 256, 0, stream>>>(h);
        affine_k<<<1, 256, 0, stream>>>(bn3_g + l * 256, bn3_b + l * 256, 2);
        apply_k<<<2048, 256, 0, stream>>>(h);
    }

    pool_k<<<N_GRAPHS_, 256, 0, stream>>>(h, pooled);
    head_k<<<N_GRAPHS_, 128, 0, stream>>>(pooled, head_w1, head_b1, head_w2, head_b2,
                                          head_w3, head_b3, (float*)d_out);
}

// Round 4
// 11552.234 us; speedup vs baseline: 1.8227x; 1.8227x over previous
//
#include <hip/hip_runtime.h>

#define N_NODES 131072
#define N_EDGES 524288
#define CCH 256
#define N_GRAPHS_ 2048
#define SEQ 64
#define LAYERS 6

typedef unsigned short US;
typedef __attribute__((ext_vector_type(8))) short v8s;           // MFMA bf16 frag (8 bf16)
typedef __attribute__((ext_vector_type(8))) unsigned short v8us; // 16B ushort vector
typedef __attribute__((ext_vector_type(4))) float v4f;           // MFMA f32 acc

__device__ __forceinline__ float b2f(US u) { return __uint_as_float(((unsigned)u) << 16); }
__device__ __forceinline__ US f2b(float f) {
    unsigned u = __float_as_uint(f);
    return (US)((u + 0x7fff + ((u >> 16) & 1)) >> 16);   // RNE
}

// small cross-kernel state (zero-init .bss; stats re-zeroed after each use)
__device__ float g_stats[512];
__device__ float g_aff1[512];
__device__ float g_aff2[512];
__device__ float g_aff3[512];
__device__ float g_peaff[40];

// ---------------------------------------------------------------- pe stats
__global__ __launch_bounds__(256) void pe_stats_k(const float* __restrict__ pe,
                                                  const float* __restrict__ g,
                                                  const float* __restrict__ b) {
    __shared__ float sbuf[256], s2buf[256];
    int ch = blockIdx.x;   // 0..19
    int tid = threadIdx.x;
    float s = 0.f, s2 = 0.f;
    for (int i = tid; i < N_NODES; i += 256) {
        float v = pe[(size_t)i * 20 + ch];
        s += v; s2 += v * v;
    }
    sbuf[tid] = s; s2buf[tid] = s2;
    __syncthreads();
    for (int off = 128; off; off >>= 1) {
        if (tid < off) { sbuf[tid] += sbuf[tid + off]; s2buf[tid] += s2buf[tid + off]; }
        __syncthreads();
    }
    if (tid == 0) {
        float mean = sbuf[0] / (float)N_NODES;
        float var  = s2buf[0] / (float)N_NODES - mean * mean;
        float a = g[ch] * rsqrtf(var + 1e-5f);
        g_peaff[ch] = a;
        g_peaff[20 + ch] = b[ch] - mean * a;
    }
}

// ---------------------------------------------------------------- embed
__global__ __launch_bounds__(256) void embed_k(const int* __restrict__ x,
                                               const float* __restrict__ pe,
                                               const float* __restrict__ node_emb,
                                               const float* __restrict__ plw,
                                               const float* __restrict__ plb,
                                               US* __restrict__ h) {
    int n = blockIdx.x;
    int tid = threadIdx.x;
    int xi = x[n];
    float v;
    if (tid < 192) {
        v = node_emb[xi * 192 + tid];
    } else {
        int j = tid - 192;
        float s = plb[j];
        #pragma unroll
        for (int k = 0; k < 20; k++) {
            float p = pe[(size_t)n * 20 + k] * g_peaff[k] + g_peaff[20 + k];
            s += p * plw[k * 64 + j];
        }
        v = s;
    }
    h[(size_t)n * CCH + tid] = f2b(v);
}

// ---------------------------------------------------------------- edge aggregation (per graph, LDS)
// z = h + sum_{e: dst} relu(h[src] + eemb[attr]); edges of graph g: [g*256,(g+1)*256)
// grid (2048, 2): col-half per blockIdx.y. Edge-parallel: half-wave per edge.
__global__ __launch_bounds__(256) void aggr_z_k(const US* __restrict__ h,
                                                const int* __restrict__ ei,
                                                const int* __restrict__ attr,
                                                const float* __restrict__ eemb,
                                                US* __restrict__ z) {
    __shared__ float zt[64][128];     // 32 KB accumulation tile
    __shared__ float em[4][128];      // edge-emb slice
    __shared__ int   es[256], ed[256], ea[256];
    int g = blockIdx.x;
    int c0 = blockIdx.y * 128;
    int tid = threadIdx.x;

    es[tid] = ei[g * 256 + tid];
    ed[tid] = ei[N_EDGES + g * 256 + tid] - g * 64;
    ea[tid] = attr[g * 256 + tid];
    #pragma unroll
    for (int i = tid; i < 512; i += 256)
        em[i >> 7][i & 127] = eemb[(i >> 7) * CCH + c0 + (i & 127)];
    // init zt = h
    #pragma unroll
    for (int i = tid; i < 4096; i += 256) {
        int r = i >> 6, cp = (i & 63) * 2;
        ushort2 hv = *(const ushort2*)(h + (size_t)(g * 64 + r) * CCH + c0 + cp);
        zt[r][cp] = b2f(hv.x); zt[r][cp + 1] = b2f(hv.y);
    }
    __syncthreads();

    int hw = tid >> 5;          // half-wave 0..7 = one edge slot
    int lane = tid & 31;
    int ca = lane * 2;          // channels ca, ca+1, ca+64, ca+65
    #pragma unroll 4
    for (int it = 0; it < 32; it++) {
        int e = it * 8 + hw;
        int src = es[e], dst = ed[e], a = ea[e];
        const US* hp = h + (size_t)src * CCH + c0 + ca;
        ushort2 h0 = *(const ushort2*)hp;
        ushort2 h1 = *(const ushort2*)(hp + 64);
        float v0 = fmaxf(b2f(h0.x) + em[a][ca],      0.f);
        float v1 = fmaxf(b2f(h0.y) + em[a][ca + 1],  0.f);
        float v2 = fmaxf(b2f(h1.x) + em[a][ca + 64], 0.f);
        float v3 = fmaxf(b2f(h1.y) + em[a][ca + 65], 0.f);
        atomicAdd(&zt[dst][ca],      v0);
        atomicAdd(&zt[dst][ca + 1],  v1);
        atomicAdd(&zt[dst][ca + 64], v2);
        atomicAdd(&zt[dst][ca + 65], v3);
    }
    __syncthreads();
    #pragma unroll
    for (int i = tid; i < 4096; i += 256) {
        int r = i >> 6, cp = (i & 63) * 2;
        ushort2 o;
        o.x = f2b(zt[r][cp]); o.y = f2b(zt[r][cp + 1]);
        *(ushort2*)(z + (size_t)(g * 64 + r) * CCH + c0 + cp) = o;
    }
}

// ---------------------------------------------------------------- MFMA bf16 GEMM
// Y[M,256-ld] cols [y*64, y*64+64) = A[M,256]@W[256, colw0...] + bias
// W is f32 with row stride ldw; W col-block offset = blockIdx.y*wstep.
// bias col index = blockIdx.y*bstep + local. mode 0: none, 1: relu, 2: += res.
// BM=128, BN=64, 4 waves x (32 rows x 64 cols).
__global__ __launch_bounds__(256) void gemm_mfma_k(const US* __restrict__ A,
                                                   const float* __restrict__ W, int ldw, int wstep,
                                                   const float* __restrict__ bias, int bstep,
                                                   const US* __restrict__ res,
                                                   US* __restrict__ Y, int mode) {
    __shared__ __align__(16) US As[128 * 40];   // [row][40] (32 K used)
    __shared__ __align__(16) US Bs[64 * 40];    // [col][40] (transposed W)
    int tid = threadIdx.x;
    size_t row0 = (size_t)blockIdx.x * 128;
    int colw0 = blockIdx.y * wstep;
    int coly0 = blockIdx.y * 64;
    int w = tid >> 6, l = tid & 63;

    int bk = tid >> 3, bc = (tid & 7) * 8;      // B staging: thread -> (k, 8 cols)
    int a_off0 = (w * 32 + (l & 15)) * 40 + (l >> 4) * 8;
    int a_off1 = a_off0 + 16 * 40;
    int b_off  = (l & 15) * 40 + (l >> 4) * 8;

    v4f acc[2][4];
    #pragma unroll
    for (int i = 0; i < 2; i++)
        #pragma unroll
        for (int t = 0; t < 4; t++) acc[i][t] = (v4f){0.f, 0.f, 0.f, 0.f};

    for (int k0 = 0; k0 < 256; k0 += 32) {
        // stage A: 128x32 bf16, 16B per thread x2
        #pragma unroll
        for (int p = 0; p < 2; p++) {
            int c = tid + p * 256;
            int row = c >> 2, ko = (c & 3) * 8;
            v8us av = *(const v8us*)(A + (row0 + row) * 256 + k0 + ko);
            *(v8us*)&As[row * 40 + ko] = av;
        }
        // stage B: 32x64 f32 -> transpose -> bf16
        {
            const float* wp = W + (size_t)(k0 + bk) * ldw + colw0 + bc;
            float4 w0 = *(const float4*)wp;
            float4 w1 = *(const float4*)(wp + 4);
            US* bp = &Bs[bc * 40 + bk];
            bp[0]   = f2b(w0.x); bp[40]  = f2b(w0.y); bp[80]  = f2b(w0.z); bp[120] = f2b(w0.w);
            bp[160] = f2b(w1.x); bp[200] = f2b(w1.y); bp[240] = f2b(w1.z); bp[280] = f2b(w1.w);
        }
        __syncthreads();
        v8s a0 = *(v8s*)&As[a_off0];
        v8s a1 = *(v8s*)&As[a_off1];
        #pragma unroll
        for (int t = 0; t < 4; t++) {
            v8s bf = *(v8s*)&Bs[b_off + t * 640];
            acc[0][t] = __builtin_amdgcn_mfma_f32_16x16x32_bf16(a0, bf, acc[0][t], 0, 0, 0);
            acc[1][t] = __builtin_amdgcn_mfma_f32_16x16x32_bf16(a1, bf, acc[1][t], 0, 0, 0);
        }
        __syncthreads();
    }
    // epilogue: lane l reg r -> row = (l>>4)*4 + r, col = l&15 (per 16x16 tile)
    int col_l = l & 15;
    int rs = (l >> 4) * 4;
    #pragma unroll
    for (int i = 0; i < 2; i++) {
        #pragma unroll
        for (int t = 0; t < 4; t++) {
            int c = coly0 + t * 16 + col_l;
            float bv = bias ? bias[blockIdx.y * bstep + t * 16 + col_l] : 0.f;
            #pragma unroll
            for (int r = 0; r < 4; r++) {
                size_t rr = row0 + w * 32 + i * 16 + rs + r;
                float v = acc[i][t][r] + bv;
                if (mode == 1) v = fmaxf(v, 0.f);
                if (mode == 2) v += b2f(res[rr * 256 + c]);
                Y[rr * 256 + c] = f2b(v);
            }
        }
    }
}

// ---------------------------------------------------------------- per-graph attention (one head)
// qkv packed: q cols 0..63, k cols 64..127, v cols 128..191 (ld 256, bf16)
__global__ __launch_bounds__(256) void attn_k(const US* __restrict__ qkv,
                                              US* __restrict__ o) {
    __shared__ float Qs[64][68], Ks[64][68], Vs[64][68];
    int g = blockIdx.x, tid = threadIdx.x;
    int r = tid >> 2;          // row 0..63
    int cg = tid & 3;          // col group
    int cb = cg * 16;
    const US* base = qkv + (size_t)(g * 64 + r) * 256 + cb;
    #pragma unroll
    for (int i = 0; i < 16; i++) {
        Qs[r][cb + i] = b2f(base[i]);
        Ks[r][cb + i] = b2f(base[64 + i]);
        Vs[r][cb + i] = b2f(base[128 + i]);
    }
    __syncthreads();
    float s[16];
    #pragma unroll
    for (int m = 0; m < 16; m++) s[m] = 0.f;
    for (int kk = 0; kk < 64; kk++) {
        float qv = Qs[r][kk];
        #pragma unroll
        for (int m = 0; m < 16; m++)
            s[m] += qv * Ks[cg + 4 * m][kk];
    }
    float mx = -1e30f;
    #pragma unroll
    for (int m = 0; m < 16; m++) { s[m] *= 0.125f; mx = fmaxf(mx, s[m]); }
    mx = fmaxf(mx, __shfl_xor(mx, 1));
    mx = fmaxf(mx, __shfl_xor(mx, 2));
    float sum = 0.f;
    #pragma unroll
    for (int m = 0; m < 16; m++) { s[m] = __expf(s[m] - mx); sum += s[m]; }
    sum += __shfl_xor(sum, 1);
    sum += __shfl_xor(sum, 2);
    float inv = 1.f / sum;
    __syncthreads();                 // Qs dead -> reuse as P
    #pragma unroll
    for (int m = 0; m < 16; m++) Qs[r][cg + 4 * m] = s[m] * inv;
    __syncthreads();
    float acc[16];
    #pragma unroll
    for (int m = 0; m < 16; m++) acc[m] = 0.f;
    for (int kk = 0; kk < 64; kk++) {
        float pv = Qs[r][kk];
        #pragma unroll
        for (int m = 0; m < 16; m++)
            acc[m] += pv * Vs[kk][cg + 4 * m];
    }
    US* ob = o + (size_t)(g * 64 + r) * 256;
    #pragma unroll
    for (int m = 0; m < 16; m++) ob[cg + 4 * m] = f2b(acc[m]);
}

// ---------------------------------------------------------------- BN stats / affine
__global__ __launch_bounds__(256) void stats_k(const US* __restrict__ Y) {
    int c = threadIdx.x;
    size_t r0 = (size_t)blockIdx.x * 128;
    float s = 0.f, s2 = 0.f;
    for (int r = 0; r < 128; r++) {
        float v = b2f(Y[(r0 + r) * CCH + c]);
        s += v; s2 += v * v;
    }
    atomicAdd(&g_stats[c], s);
    atomicAdd(&g_stats[CCH + c], s2);
}

__global__ __launch_bounds__(256) void affine_k(const float* __restrict__ g,
                                                const float* __restrict__ b, int sel) {
    int c = threadIdx.x;
    float mean = g_stats[c] / (float)N_NODES;
    float var  = g_stats[CCH + c] / (float)N_NODES - mean * mean;
    float a = g[c] * rsqrtf(var + 1e-5f);
    float* dst = (sel == 0) ? g_aff1 : (sel == 1) ? g_aff2 : g_aff3;
    dst[c] = a;
    dst[CCH + c] = b[c] - mean * a;
    g_stats[c] = 0.f;          // re-zero for next stats pass (deterministic invariant)
    g_stats[CCH + c] = 0.f;
}

// ---------------------------------------------------------------- elementwise
__global__ __launch_bounds__(256) void combine_k(const US* __restrict__ y1,
                                                 const US* __restrict__ y2,
                                                 US* __restrict__ out) {
    size_t i = (size_t)blockIdx.x * 256 + threadIdx.x;
    size_t stride = (size_t)gridDim.x * 256;
    for (; i < (size_t)N_NODES * CCH; i += stride) {
        int c = (int)(i & 255);
        float v = (b2f(y1[i]) * g_aff1[c] + g_aff1[CCH + c]) +
                  (b2f(y2[i]) * g_aff2[c] + g_aff2[CCH + c]);
        out[i] = f2b(v);
    }
}

__global__ __launch_bounds__(256) void apply_k(US* __restrict__ h) {
    size_t i = (size_t)blockIdx.x * 256 + threadIdx.x;
    size_t stride = (size_t)gridDim.x * 256;
    for (; i < (size_t)N_NODES * CCH; i += stride) {
        int c = (int)(i & 255);
        h[i] = f2b(b2f(h[i]) * g_aff3[c] + g_aff3[CCH + c]);
    }
}

// ---------------------------------------------------------------- pool + head
__global__ __launch_bounds__(256) void pool_k(const US* __restrict__ h,
                                              float* __restrict__ pooled) {
    int g = blockIdx.x, c = threadIdx.x;
    float s = 0.f;
    for (int ss = 0; ss < SEQ; ss++) s += b2f(h[((size_t)g * SEQ + ss) * CCH + c]);
    pooled[(size_t)g * CCH + c] = s;
}

__global__ __launch_bounds__(128) void head_k(const float* __restrict__ pooled,
                                              const float* __restrict__ w1, const float* __restrict__ b1,
                                              const float* __restrict__ w2, const float* __restrict__ b2,
                                              const float* __restrict__ w3, const float* __restrict__ b3,
                                              float* __restrict__ outp) {
    __shared__ float p[256], t1[128], t2[64];
    int g = blockIdx.x, tid = threadIdx.x;
    p[tid] = pooled[(size_t)g * CCH + tid];
    p[tid + 128] = pooled[(size_t)g * CCH + 128 + tid];
    __syncthreads();
    float s = b1[tid];
    for (int k = 0; k < 256; k++) s += p[k] * w1[k * 128 + tid];
    t1[tid] = fmaxf(s, 0.f);
    __syncthreads();
    if (tid < 64) {
        float s2 = b2[tid];
        for (int k = 0; k < 128; k++) s2 += t1[k] * w2[k * 64 + tid];
        t2[tid] = fmaxf(s2, 0.f);
    }
    __syncthreads();
    if (tid == 0) {
        float s3 = b3[0];
        for (int k = 0; k < 64; k++) s3 += t2[k] * w3[k];
        outp[g] = s3;
    }
}

// ================================================================ launch
extern "C" void kernel_launch(void* const* d_in, const int* in_sizes, int n_in,
                              void* d_out, int out_size, void* d_ws, size_t ws_size,
                              hipStream_t stream) {
    const int*   x         = (const int*)  d_in[0];
    const float* pe        = (const float*)d_in[1];
    const int*   ei        = (const int*)  d_in[2];
    const int*   eattr     = (const int*)  d_in[3];
    const float* node_emb  = (const float*)d_in[5];
    const float* pe_lin_w  = (const float*)d_in[6];
    const float* pe_lin_b  = (const float*)d_in[7];
    const float* pe_norm_g = (const float*)d_in[8];
    const float* pe_norm_b = (const float*)d_in[9];
    const float* edge_emb  = (const float*)d_in[10];
    const float* conv_w1   = (const float*)d_in[11];
    const float* conv_b1   = (const float*)d_in[12];
    const float* conv_w2   = (const float*)d_in[13];
    const float* conv_b2   = (const float*)d_in[14];
    const float* attn_in_w = (const float*)d_in[15];
    const float* attn_in_b = (const float*)d_in[16];
    const float* attn_out_w= (const float*)d_in[17];
    const float* attn_out_b= (const float*)d_in[18];
    const float* bn1_g     = (const float*)d_in[19];
    const float* bn1_b     = (const float*)d_in[20];
    const float* bn2_g     = (const float*)d_in[21];
    const float* bn2_b     = (const float*)d_in[22];
    const float* bn3_g     = (const float*)d_in[23];
    const float* bn3_b     = (const float*)d_in[24];
    const float* mlp_w1    = (const float*)d_in[25];
    const float* mlp_b1    = (const float*)d_in[26];
    const float* mlp_w2    = (const float*)d_in[27];
    const float* mlp_b2    = (const float*)d_in[28];
    const float* head_w1   = (const float*)d_in[29];
    const float* head_b1   = (const float*)d_in[30];
    const float* head_w2   = (const float*)d_in[31];
    const float* head_b2   = (const float*)d_in[32];
    const float* head_w3   = (const float*)d_in[33];
    const float* head_b3   = (const float*)d_in[34];
    (void)in_sizes; (void)n_in; (void)out_size; (void)ws_size;

    // workspace: exactly 4 x 64 MB bf16 [N,256] buffers = 256 MB total
    char* ws = (char*)d_ws;
    US* h    = (US*)(ws);
    US* A    = (US*)(ws + 67108864ULL);
    US* B    = (US*)(ws + 134217728ULL);
    US* C    = (US*)(ws + 201326592ULL);
    float* pooled = (float*)(ws + 67108864ULL);   // reuses A (dead after layer loop)

    pe_stats_k<<<20, 256, 0, stream>>>(pe, pe_norm_g, pe_norm_b);
    embed_k<<<N_NODES, 256, 0, stream>>>(x, pe, node_emb, pe_lin_w, pe_lin_b, h);

    for (int l = 0; l < LAYERS; l++) {
        const float* cw1 = conv_w1 + (size_t)l * 65536;
        const float* cw2 = conv_w2 + (size_t)l * 65536;
        const float* aiw = attn_in_w + (size_t)l * 196608;
        const float* aib = attn_in_b + (size_t)l * 768;
        const float* aow = attn_out_w + (size_t)l * 65536;
        const float* mw1 = mlp_w1 + (size_t)l * 131072;
        const float* mb1 = mlp_b1 + (size_t)l * 512;
        const float* mw2 = mlp_w2 + (size_t)l * 131072;

        // ---- local GINEConv ----
        aggr_z_k<<<dim3(N_GRAPHS_, 2), 256, 0, stream>>>(h, ei, eattr, edge_emb, A); // z=A
        gemm_mfma_k<<<dim3(1024, 4), 256, 0, stream>>>(A, cw1, 256, 64,
                                                       conv_b1 + l * 256, 64, nullptr, B, 1); // t1
        gemm_mfma_k<<<dim3(1024, 4), 256, 0, stream>>>(B, cw2, 256, 64,
                                                       conv_b2 + l * 256, 64, h, C, 2);       // y1
        stats_k<<<1024, 256, 0, stream>>>(C);
        affine_k<<<1, 256, 0, stream>>>(bn1_g + l * 256, bn1_b + l * 256, 0);

        // ---- global attention (per head; q|k|v packed in A cols 0..191, o packed in B) ----
        for (int hh = 0; hh < 4; hh++) {
            gemm_mfma_k<<<dim3(1024, 3), 256, 0, stream>>>(h, aiw + hh * 64, 768, 256,
                                                           aib + hh * 64, 256, nullptr, A, 0);
            attn_k<<<N_GRAPHS_, 256, 0, stream>>>(A, B + hh * 64);                            // o_hh
        }
        gemm_mfma_k<<<dim3(1024, 4), 256, 0, stream>>>(B, aow, 256, 64,
                                                       attn_out_b + l * 256, 64, h, h, 2);    // y2 -> h
        stats_k<<<1024, 256, 0, stream>>>(h);
        affine_k<<<1, 256, 0, stream>>>(bn2_g + l * 256, bn2_b + l * 256, 1);

        // ---- combine + FFN (512-wide hidden split into two 256 halves) ----
        combine_k<<<2048, 256, 0, stream>>>(C, h, A);                                         // out=A
        gemm_mfma_k<<<dim3(1024, 4), 256, 0, stream>>>(A, mw1, 512, 64,
                                                       mb1, 64, nullptr, B, 1);               // tA
        gemm_mfma_k<<<dim3(1024, 4), 256, 0, stream>>>(B, mw2, 256, 64,
                                                       mlp_b2 + l * 256, 64, A, C, 2);        // partial
        gemm_mfma_k<<<dim3(1024, 4), 256, 0, stream>>>(A, mw1 + 256, 512, 64,
                                                       mb1 + 256, 64, nullptr, B, 1);         // tB
        gemm_mfma_k<<<dim3(1024, 4), 256, 0, stream>>>(B, mw2 + 65536, 256, 64,
                                                       nullptr, 64, C, h, 2);                 // y3 -> h
        stats_k<<<1024, 256, 0, stream>>>(h);
        affine_k<<<1, 256, 0, stream>>>(bn3_g + l * 256, bn3_b + l * 256, 2);
        apply_k<<<2048, 256, 0, stream>>>(h);
    }

    pool_k<<<N_GRAPHS_, 256, 0, stream>>>(h, pooled);
    head_k<<<N_GRAPHS_, 128, 0, stream>>>(pooled, head_w1, head_b1, head_w2, head_b2,
                                          head_w3, head_b3, (float*)d_out);
}

// Round 6
// 7113.966 us; speedup vs baseline: 2.9598x; 1.6239x over previous
//
#include <hip/hip_runtime.h>

#define N_NODES 131072
#define N_EDGES 524288
#define CCH 256
#define N_GRAPHS_ 2048
#define SEQ 64
#define LAYERS 6

typedef unsigned short US;
typedef __attribute__((ext_vector_type(8))) short v8s;           // MFMA bf16 frag
typedef __attribute__((ext_vector_type(8))) unsigned short v8us; // 16B ushort vector
typedef __attribute__((ext_vector_type(4))) float v4f;           // MFMA f32 acc

__device__ __forceinline__ float b2f(US u) { return __uint_as_float(((unsigned)u) << 16); }
__device__ __forceinline__ US f2b(float f) {
    unsigned u = __float_as_uint(f);
    return (US)((u + 0x7fff + ((u >> 16) & 1)) >> 16);   // RNE
}

// cross-kernel state — referenced ONLY inside device code (never from host!)
__device__ float g_stats[512];
__device__ float g_aff1[512];
__device__ float g_aff2[512];
__device__ float g_aff3[512];
__device__ float g_peaff[40];
__device__ US    g_wt[6 * 655360];          // per-layer transposed bf16 weights
__device__ int   g_csr[N_EDGES];            // per-graph dst-sorted edges: srcLocal | attr<<6
__device__ int   g_off[N_GRAPHS_ * 65];     // per-graph CSR offsets

// ---------------------------------------------------------------- weight transpose f32[K][C] -> bf16[C][K]
__global__ __launch_bounds__(256) void wt_k(const float* __restrict__ cw1, const float* __restrict__ cw2,
                                            const float* __restrict__ aiw, const float* __restrict__ aow,
                                            const float* __restrict__ mw1, const float* __restrict__ mw2) {
    __shared__ float t[64][65];
    int b = blockIdx.x;
    int l = b / 160, r = b % 160;
    const float* src; int ldw, ldk, ctiles; size_t doff;
    if (r < 16)      { src = cw1 + (size_t)l * 65536;  ldw = 256; ldk = 256; ctiles = 4;  doff = 0;      }
    else if (r < 32) { src = cw2 + (size_t)l * 65536;  ldw = 256; ldk = 256; ctiles = 4;  doff = 65536;  r -= 16; }
    else if (r < 80) { src = aiw + (size_t)l * 196608; ldw = 768; ldk = 256; ctiles = 12; doff = 131072; r -= 32; }
    else if (r < 96) { src = aow + (size_t)l * 65536;  ldw = 256; ldk = 256; ctiles = 4;  doff = 327680; r -= 80; }
    else if (r < 128){ src = mw1 + (size_t)l * 131072; ldw = 512; ldk = 256; ctiles = 8;  doff = 393216; r -= 96; }
    else             { src = mw2 + (size_t)l * 131072; ldw = 256; ldk = 512; ctiles = 4;  doff = 524288; r -= 128; }
    int kt = r / ctiles, ct = r % ctiles;
    int k0 = kt * 64, c0 = ct * 64;
    US* dst = g_wt + (size_t)l * 655360 + doff;
    int tid = threadIdx.x;
    int rr = tid >> 4, c4 = (tid & 15) * 4;
    #pragma unroll
    for (int j = 0; j < 4; j++) {
        float4 v = *(const float4*)(src + (size_t)(k0 + rr + j * 16) * ldw + c0 + c4);
        t[rr + j * 16][c4 + 0] = v.x; t[rr + j * 16][c4 + 1] = v.y;
        t[rr + j * 16][c4 + 2] = v.z; t[rr + j * 16][c4 + 3] = v.w;
    }
    __syncthreads();
    #pragma unroll
    for (int j = 0; j < 4; j++) {
        int crow = rr + j * 16;
        ushort4 o;
        o.x = f2b(t[c4 + 0][crow]); o.y = f2b(t[c4 + 1][crow]);
        o.z = f2b(t[c4 + 2][crow]); o.w = f2b(t[c4 + 3][crow]);
        *(ushort4*)(dst + (size_t)(c0 + crow) * ldk + k0 + c4) = o;
    }
}

// ---------------------------------------------------------------- CSR build (once per launch)
__global__ __launch_bounds__(256) void csr_k(const int* __restrict__ ei,
                                             const int* __restrict__ attr) {
    __shared__ int deg[64], off[65];
    int g = blockIdx.x, tid = threadIdx.x;
    if (tid < 64) deg[tid] = 0;
    __syncthreads();
    int e = g * 256 + tid;
    int d = ei[N_EDGES + e] - g * 64;
    int slot = atomicAdd(&deg[d], 1);
    __syncthreads();
    if (tid == 0) {
        off[0] = 0;
        for (int i = 0; i < 64; i++) off[i + 1] = off[i] + deg[i];
    }
    __syncthreads();
    g_csr[g * 256 + off[d] + slot] = (ei[e] - g * 64) | (attr[e] << 6);
    if (tid < 65) g_off[g * 65 + tid] = off[tid];
}

// ---------------------------------------------------------------- pe stats
__global__ __launch_bounds__(256) void pe_stats_k(const float* __restrict__ pe,
                                                  const float* __restrict__ g,
                                                  const float* __restrict__ b) {
    __shared__ float sbuf[256], s2buf[256];
    int ch = blockIdx.x;   // 0..19
    int tid = threadIdx.x;
    float s = 0.f, s2 = 0.f;
    for (int i = tid; i < N_NODES; i += 256) {
        float v = pe[(size_t)i * 20 + ch];
        s += v; s2 += v * v;
    }
    sbuf[tid] = s; s2buf[tid] = s2;
    __syncthreads();
    for (int off = 128; off; off >>= 1) {
        if (tid < off) { sbuf[tid] += sbuf[tid + off]; s2buf[tid] += s2buf[tid + off]; }
        __syncthreads();
    }
    if (tid == 0) {
        float mean = sbuf[0] / (float)N_NODES;
        float var  = s2buf[0] / (float)N_NODES - mean * mean;
        float a = g[ch] * rsqrtf(var + 1e-5f);
        g_peaff[ch] = a;
        g_peaff[20 + ch] = b[ch] - mean * a;
    }
}

// ---------------------------------------------------------------- embed
__global__ __launch_bounds__(256) void embed_k(const int* __restrict__ x,
                                               const float* __restrict__ pe,
                                               const float* __restrict__ node_emb,
                                               const float* __restrict__ plw,
                                               const float* __restrict__ plb,
                                               US* __restrict__ h) {
    int n = blockIdx.x;
    int tid = threadIdx.x;
    int xi = x[n];
    float v;
    if (tid < 192) {
        v = node_emb[xi * 192 + tid];
    } else {
        int j = tid - 192;
        float s = plb[j];
        #pragma unroll
        for (int k = 0; k < 20; k++) {
            float p = pe[(size_t)n * 20 + k] * g_peaff[k] + g_peaff[20 + k];
            s += p * plw[k * 64 + j];
        }
        v = s;
    }
    h[(size_t)n * CCH + tid] = f2b(v);
}

// ---------------------------------------------------------------- edge aggregation: CSR, no atomics
// z = h + sum_{e->dst} relu(h[src] + eemb[attr]); one wg per graph.
__global__ __launch_bounds__(256) void aggr_z_k(const US* __restrict__ h,
                                                const float* __restrict__ eemb,
                                                US* __restrict__ z) {
    __shared__ US ht[64 * 264];        // h-tile, padded row stride 264
    __shared__ float em[4 * 260];      // edge-emb, padded stride 260
    __shared__ int off[65], ce[256];
    int g = blockIdx.x, tid = threadIdx.x;
    for (int v = tid; v < 2048; v += 256) {
        int row = v >> 5, seg = (v & 31) * 8;
        *(v8us*)&ht[row * 264 + seg] = *(const v8us*)(h + (size_t)(g * 64 + row) * 256 + seg);
    }
    for (int i = tid; i < 1024; i += 256)
        em[(i >> 8) * 260 + (i & 255)] = eemb[(i >> 8) * 256 + (i & 255)];
    ce[tid] = g_csr[g * 256 + tid];
    if (tid < 65) off[tid] = g_off[g * 65 + tid];
    __syncthreads();

    int dst = tid >> 2, cq = (tid & 3) * 4;   // thread owns chans cq + i*16, i=0..15
    float acc[64];
    #pragma unroll
    for (int i = 0; i < 64; i++) acc[i] = 0.f;
    int e1 = off[dst + 1];
    for (int e = off[dst]; e < e1; e++) {
        int val = ce[e];
        int src = val & 63, a = (val >> 6) & 3;
        #pragma unroll
        for (int i = 0; i < 16; i++) {
            int c = cq + i * 16;
            ushort4 hv = *(ushort4*)&ht[src * 264 + c];
            float4 ev = *(float4*)&em[a * 260 + c];
            acc[i * 4 + 0] += fmaxf(b2f(hv.x) + ev.x, 0.f);
            acc[i * 4 + 1] += fmaxf(b2f(hv.y) + ev.y, 0.f);
            acc[i * 4 + 2] += fmaxf(b2f(hv.z) + ev.z, 0.f);
            acc[i * 4 + 3] += fmaxf(b2f(hv.w) + ev.w, 0.f);
        }
    }
    US* zp = z + (size_t)(g * 64 + dst) * 256;
    #pragma unroll
    for (int i = 0; i < 16; i++) {
        int c = cq + i * 16;
        ushort4 hv = *(ushort4*)&ht[dst * 264 + c];
        ushort4 o;
        o.x = f2b(b2f(hv.x) + acc[i * 4 + 0]);
        o.y = f2b(b2f(hv.y) + acc[i * 4 + 1]);
        o.z = f2b(b2f(hv.z) + acc[i * 4 + 2]);
        o.w = f2b(b2f(hv.w) + acc[i * 4 + 3]);
        *(ushort4*)(zp + c) = o;
    }
}

// ---------------------------------------------------------------- MFMA bf16 GEMM (pre-transposed bf16 W in g_wt)
// Wt = g_wt + woff (resolved IN DEVICE CODE). Y cols [y*64, y*64+64) =
// A[M,256] @ Wt[colw0+col][k] + bias[colw0+col]; colw0 = colbase + y*wstep.
// ld of A/res/Y = 256. mode 0 none, 1 relu, 2 +=res
__global__ __launch_bounds__(256) void gemm_mfma_k(const US* __restrict__ A,
                                                   size_t woff, int ldk,
                                                   int colbase, int wstep,
                                                   const float* __restrict__ bias,
                                                   const US* __restrict__ res,
                                                   US* __restrict__ Y, int mode) {
    const US* __restrict__ Wt = g_wt + woff;
    __shared__ __align__(16) US As[128 * 40];
    __shared__ __align__(16) US Bs[64 * 40];
    int tid = threadIdx.x;
    size_t row0 = (size_t)blockIdx.x * 128;
    int colw0 = colbase + blockIdx.y * wstep;
    int coly0 = blockIdx.y * 64;
    int w = tid >> 6, l = tid & 63;

    int sb_col = tid >> 2, sb_ko = (tid & 3) * 8;
    int a_off0 = (w * 32 + (l & 15)) * 40 + (l >> 4) * 8;
    int a_off1 = a_off0 + 16 * 40;
    int b_off  = (l & 15) * 40 + (l >> 4) * 8;

    v4f acc[2][4];
    #pragma unroll
    for (int i = 0; i < 2; i++)
        #pragma unroll
        for (int t = 0; t < 4; t++) acc[i][t] = (v4f){0.f, 0.f, 0.f, 0.f};

    for (int k0 = 0; k0 < 256; k0 += 32) {
        #pragma unroll
        for (int p = 0; p < 2; p++) {
            int cidx = tid + p * 256;
            int row = cidx >> 2, ko = (cidx & 3) * 8;
            *(v8us*)&As[row * 40 + ko] = *(const v8us*)(A + (row0 + row) * 256 + k0 + ko);
        }
        *(v8us*)&Bs[sb_col * 40 + sb_ko] =
            *(const v8us*)(Wt + (size_t)(colw0 + sb_col) * ldk + k0 + sb_ko);
        __syncthreads();
        v8s a0 = *(v8s*)&As[a_off0];
        v8s a1 = *(v8s*)&As[a_off1];
        #pragma unroll
        for (int t = 0; t < 4; t++) {
            v8s bf = *(v8s*)&Bs[b_off + t * 640];
            acc[0][t] = __builtin_amdgcn_mfma_f32_16x16x32_bf16(a0, bf, acc[0][t], 0, 0, 0);
            acc[1][t] = __builtin_amdgcn_mfma_f32_16x16x32_bf16(a1, bf, acc[1][t], 0, 0, 0);
        }
        __syncthreads();
    }
    int col_l = l & 15;
    int rs = (l >> 4) * 4;
    #pragma unroll
    for (int i = 0; i < 2; i++) {
        #pragma unroll
        for (int t = 0; t < 4; t++) {
            int c = coly0 + t * 16 + col_l;
            float bv = bias ? bias[colw0 + t * 16 + col_l] : 0.f;
            #pragma unroll
            for (int r = 0; r < 4; r++) {
                size_t rr = row0 + w * 32 + i * 16 + rs + r;
                float v = acc[i][t][r] + bv;
                if (mode == 1) v = fmaxf(v, 0.f);
                if (mode == 2) v += b2f(res[rr * 256 + c]);
                Y[rr * 256 + c] = f2b(v);
            }
        }
    }
}

// ---------------------------------------------------------------- per-graph attention (one head)
__global__ __launch_bounds__(256) void attn_k(const US* __restrict__ qkv,
                                              US* __restrict__ o) {
    __shared__ float Qs[64][68], Ks[64][68], Vs[64][68];
    int g = blockIdx.x, tid = threadIdx.x;
    int r = tid >> 2;
    int cg = tid & 3;
    int cb = cg * 16;
    const US* base = qkv + (size_t)(g * 64 + r) * 256 + cb;
    #pragma unroll
    for (int i = 0; i < 16; i++) {
        Qs[r][cb + i] = b2f(base[i]);
        Ks[r][cb + i] = b2f(base[64 + i]);
        Vs[r][cb + i] = b2f(base[128 + i]);
    }
    __syncthreads();
    float s[16];
    #pragma unroll
    for (int m = 0; m < 16; m++) s[m] = 0.f;
    for (int kk = 0; kk < 64; kk++) {
        float qv = Qs[r][kk];
        #pragma unroll
        for (int m = 0; m < 16; m++)
            s[m] += qv * Ks[cg + 4 * m][kk];
    }
    float mx = -1e30f;
    #pragma unroll
    for (int m = 0; m < 16; m++) { s[m] *= 0.125f; mx = fmaxf(mx, s[m]); }
    mx = fmaxf(mx, __shfl_xor(mx, 1));
    mx = fmaxf(mx, __shfl_xor(mx, 2));
    float sum = 0.f;
    #pragma unroll
    for (int m = 0; m < 16; m++) { s[m] = __expf(s[m] - mx); sum += s[m]; }
    sum += __shfl_xor(sum, 1);
    sum += __shfl_xor(sum, 2);
    float inv = 1.f / sum;
    __syncthreads();
    #pragma unroll
    for (int m = 0; m < 16; m++) Qs[r][cg + 4 * m] = s[m] * inv;
    __syncthreads();
    float acc[16];
    #pragma unroll
    for (int m = 0; m < 16; m++) acc[m] = 0.f;
    for (int kk = 0; kk < 64; kk++) {
        float pv = Qs[r][kk];
        #pragma unroll
        for (int m = 0; m < 16; m++)
            acc[m] += pv * Vs[kk][cg + 4 * m];
    }
    US* ob = o + (size_t)(g * 64 + r) * 256;
    #pragma unroll
    for (int m = 0; m < 16; m++) ob[cg + 4 * m] = f2b(acc[m]);
}

// ---------------------------------------------------------------- BN stats / affine
__global__ __launch_bounds__(256) void stats_k(const US* __restrict__ Y) {
    int c = threadIdx.x;
    size_t r0 = (size_t)blockIdx.x * 1024;
    float s = 0.f, s2 = 0.f;
    for (int r = 0; r < 1024; r++) {
        float v = b2f(Y[(r0 + r) * CCH + c]);
        s += v; s2 += v * v;
    }
    atomicAdd(&g_stats[c], s);
    atomicAdd(&g_stats[CCH + c], s2);
}

__global__ __launch_bounds__(256) void affine_k(const float* __restrict__ g,
                                                const float* __restrict__ b, int sel) {
    int c = threadIdx.x;
    float mean = g_stats[c] / (float)N_NODES;
    float var  = g_stats[CCH + c] / (float)N_NODES - mean * mean;
    float a = g[c] * rsqrtf(var + 1e-5f);
    float* dst = (sel == 0) ? g_aff1 : (sel == 1) ? g_aff2 : g_aff3;
    dst[c] = a;
    dst[CCH + c] = b[c] - mean * a;
    g_stats[c] = 0.f;
    g_stats[CCH + c] = 0.f;
}

// ---------------------------------------------------------------- elementwise (v8us vectorized)
__global__ __launch_bounds__(256) void combine_k(const US* __restrict__ y1,
                                                 const US* __restrict__ y2,
                                                 US* __restrict__ out) {
    size_t idx = (size_t)blockIdx.x * 256 + threadIdx.x;
    size_t stride = (size_t)gridDim.x * 256;
    for (; idx < (size_t)N_NODES * CCH / 8; idx += stride) {
        size_t i = idx * 8;
        int c = (int)(i & 255);
        v8us a = *(const v8us*)(y1 + i);
        v8us b = *(const v8us*)(y2 + i);
        v8us o;
        #pragma unroll
        for (int j = 0; j < 8; j++) {
            float v = b2f(a[j]) * g_aff1[c + j] + g_aff1[CCH + c + j] +
                      b2f(b[j]) * g_aff2[c + j] + g_aff2[CCH + c + j];
            o[j] = f2b(v);
        }
        *(v8us*)(out + i) = o;
    }
}

__global__ __launch_bounds__(256) void apply_k(US* __restrict__ h) {
    size_t idx = (size_t)blockIdx.x * 256 + threadIdx.x;
    size_t stride = (size_t)gridDim.x * 256;
    for (; idx < (size_t)N_NODES * CCH / 8; idx += stride) {
        size_t i = idx * 8;
        int c = (int)(i & 255);
        v8us a = *(const v8us*)(h + i);
        v8us o;
        #pragma unroll
        for (int j = 0; j < 8; j++)
            o[j] = f2b(b2f(a[j]) * g_aff3[c + j] + g_aff3[CCH + c + j]);
        *(v8us*)(h + i) = o;
    }
}

// ---------------------------------------------------------------- pool + head
__global__ __launch_bounds__(256) void pool_k(const US* __restrict__ h,
                                              float* __restrict__ pooled) {
    int g = blockIdx.x, c = threadIdx.x;
    float s = 0.f;
    for (int ss = 0; ss < SEQ; ss++) s += b2f(h[((size_t)g * SEQ + ss) * CCH + c]);
    pooled[(size_t)g * CCH + c] = s;
}

__global__ __launch_bounds__(128) void head_k(const float* __restrict__ pooled,
                                              const float* __restrict__ w1, const float* __restrict__ b1,
                                              const float* __restrict__ w2, const float* __restrict__ b2,
                                              const float* __restrict__ w3, const float* __restrict__ b3,
                                              float* __restrict__ outp) {
    __shared__ float p[256], t1[128], t2[64];
    int g = blockIdx.x, tid = threadIdx.x;
    p[tid] = pooled[(size_t)g * CCH + tid];
    p[tid + 128] = pooled[(size_t)g * CCH + 128 + tid];
    __syncthreads();
    float s = b1[tid];
    for (int k = 0; k < 256; k++) s += p[k] * w1[k * 128 + tid];
    t1[tid] = fmaxf(s, 0.f);
    __syncthreads();
    if (tid < 64) {
        float s2 = b2[tid];
        for (int k = 0; k < 128; k++) s2 += t1[k] * w2[k * 64 + tid];
        t2[tid] = fmaxf(s2, 0.f);
    }
    __syncthreads();
    if (tid == 0) {
        float s3 = b3[0];
        for (int k = 0; k < 64; k++) s3 += t2[k] * w3[k];
        outp[g] = s3;
    }
}

// ================================================================ launch
extern "C" void kernel_launch(void* const* d_in, const int* in_sizes, int n_in,
                              void* d_out, int out_size, void* d_ws, size_t ws_size,
                              hipStream_t stream) {
    const int*   x         = (const int*)  d_in[0];
    const float* pe        = (const float*)d_in[1];
    const int*   ei        = (const int*)  d_in[2];
    const int*   eattr     = (const int*)  d_in[3];
    const float* node_emb  = (const float*)d_in[5];
    const float* pe_lin_w  = (const float*)d_in[6];
    const float* pe_lin_b  = (const float*)d_in[7];
    const float* pe_norm_g = (const float*)d_in[8];
    const float* pe_norm_b = (const float*)d_in[9];
    const float* edge_emb  = (const float*)d_in[10];
    const float* conv_w1   = (const float*)d_in[11];
    const float* conv_b1   = (const float*)d_in[12];
    const float* conv_w2   = (const float*)d_in[13];
    const float* conv_b2   = (const float*)d_in[14];
    const float* attn_in_w = (const float*)d_in[15];
    const float* attn_in_b = (const float*)d_in[16];
    const float* attn_out_w= (const float*)d_in[17];
    const float* attn_out_b= (const float*)d_in[18];
    const float* bn1_g     = (const float*)d_in[19];
    const float* bn1_b     = (const float*)d_in[20];
    const float* bn2_g     = (const float*)d_in[21];
    const float* bn2_b     = (const float*)d_in[22];
    const float* bn3_g     = (const float*)d_in[23];
    const float* bn3_b     = (const float*)d_in[24];
    const float* mlp_w1    = (const float*)d_in[25];
    const float* mlp_b1    = (const float*)d_in[26];
    const float* mlp_w2    = (const float*)d_in[27];
    const float* mlp_b2    = (const float*)d_in[28];
    const float* head_w1   = (const float*)d_in[29];
    const float* head_b1   = (const float*)d_in[30];
    const float* head_w2   = (const float*)d_in[31];
    const float* head_b2   = (const float*)d_in[32];
    const float* head_w3   = (const float*)d_in[33];
    const float* head_b3   = (const float*)d_in[34];
    (void)in_sizes; (void)n_in; (void)out_size; (void)ws_size;

    // workspace: 4 x 64 MB bf16 [N,256] buffers = 256 MB total (proven safe in R3/R4)
    char* ws = (char*)d_ws;
    US* h = (US*)(ws);
    US* A = (US*)(ws + 67108864ULL);
    US* B = (US*)(ws + 134217728ULL);
    US* C = (US*)(ws + 201326592ULL);
    float* pooled = (float*)(ws + 67108864ULL);   // reuses A (dead after layer loop)

    wt_k<<<960, 256, 0, stream>>>(conv_w1, conv_w2, attn_in_w, attn_out_w, mlp_w1, mlp_w2);
    csr_k<<<N_GRAPHS_, 256, 0, stream>>>(ei, eattr);
    pe_stats_k<<<20, 256, 0, stream>>>(pe, pe_norm_g, pe_norm_b);
    embed_k<<<N_NODES, 256, 0, stream>>>(x, pe, node_emb, pe_lin_w, pe_lin_b, h);

    for (int l = 0; l < LAYERS; l++) {
        size_t wl = (size_t)l * 655360;   // offset into g_wt (resolved device-side)

        // ---- local GINEConv ----
        aggr_z_k<<<N_GRAPHS_, 256, 0, stream>>>(h, edge_emb, A);                       // z=A
        gemm_mfma_k<<<dim3(1024, 4), 256, 0, stream>>>(A, wl, 256, 0, 64,
                                                       conv_b1 + l * 256, nullptr, B, 1);      // t1
        gemm_mfma_k<<<dim3(1024, 4), 256, 0, stream>>>(B, wl + 65536, 256, 0, 64,
                                                       conv_b2 + l * 256, h, C, 2);            // y1
        stats_k<<<128, 256, 0, stream>>>(C);
        affine_k<<<1, 256, 0, stream>>>(bn1_g + l * 256, bn1_b + l * 256, 0);

        // ---- global attention (per head; q|k|v packed in A cols 0..191, o packed in B) ----
        for (int hh = 0; hh < 4; hh++) {
            gemm_mfma_k<<<dim3(1024, 3), 256, 0, stream>>>(h, wl + 131072, 256,
                                                           hh * 64, 256,
                                                           attn_in_b + l * 768, nullptr, A, 0);
            attn_k<<<N_GRAPHS_, 256, 0, stream>>>(A, B + hh * 64);
        }
        gemm_mfma_k<<<dim3(1024, 4), 256, 0, stream>>>(B, wl + 327680, 256, 0, 64,
                                                       attn_out_b + l * 256, h, h, 2);         // y2->h
        stats_k<<<128, 256, 0, stream>>>(h);
        affine_k<<<1, 256, 0, stream>>>(bn2_g + l * 256, bn2_b + l * 256, 1);

        // ---- combine + FFN (hidden split into two 256 halves) ----
        combine_k<<<2048, 256, 0, stream>>>(C, h, A);                                          // out=A
        gemm_mfma_k<<<dim3(1024, 4), 256, 0, stream>>>(A, wl + 393216, 256, 0, 64,
                                                       mlp_b1 + l * 512, nullptr, B, 1);       // tA
        gemm_mfma_k<<<dim3(1024, 4), 256, 0, stream>>>(B, wl + 524288, 512, 0, 64,
                                                       mlp_b2 + l * 256, A, C, 2);             // partial
        gemm_mfma_k<<<dim3(1024, 4), 256, 0, stream>>>(A, wl + 393216, 256, 256, 64,
                                                       mlp_b1 + l * 512, nullptr, B, 1);       // tB
        gemm_mfma_k<<<dim3(1024, 4), 256, 0, stream>>>(B, wl + 524288 + 256, 512, 0, 64,
                                                       nullptr, C, h, 2);                      // y3->h
        stats_k<<<128, 256, 0, stream>>>(h);
        affine_k<<<1, 256, 0, stream>>>(bn3_g + l * 256, bn3_b + l * 256, 2);
        apply_k<<<2048, 256, 0, stream>>>(h);
    }

    pool_k<<<N_GRAPHS_, 256, 0, stream>>>(h, pooled);
    head_k<<<N_GRAPHS_, 128, 0, stream>>>(pooled, head_w1, head_b1, head_w2, head_b2,
                                          head_w3, head_b3, (float*)d_out);
}

// Round 7
// 6087.698 us; speedup vs baseline: 3.4588x; 1.1686x over previous
//
#include <hip/hip_runtime.h>

#define N_NODES 131072
#define N_EDGES 524288
#define CCH 256
#define N_GRAPHS_ 2048
#define SEQ 64
#define LAYERS 6

typedef unsigned short US;
typedef __attribute__((ext_vector_type(8))) short v8s;           // MFMA bf16 frag
typedef __attribute__((ext_vector_type(8))) unsigned short v8us; // 16B ushort vector
typedef __attribute__((ext_vector_type(4))) float v4f;           // MFMA f32 acc

__device__ __forceinline__ float b2f(US u) { return __uint_as_float(((unsigned)u) << 16); }
__device__ __forceinline__ US f2b(float f) {
    unsigned u = __float_as_uint(f);
    return (US)((u + 0x7fff + ((u >> 16) & 1)) >> 16);   // RNE
}

// cross-kernel state — referenced ONLY inside device code (never from host!)
__device__ float g_stats[512];
__device__ float g_aff1[512];
__device__ float g_aff2[512];
__device__ float g_aff3[512];
__device__ float g_pe[40];
__device__ float g_peaff[40];
__device__ US    g_wt[6 * 655360];          // per-layer transposed bf16 weights
__device__ int   g_csr[N_EDGES];            // per-graph dst-sorted edges: srcLocal | attr<<6
__device__ int   g_off[N_GRAPHS_ * 65];     // per-graph CSR offsets

// ---------------------------------------------------------------- weight transpose f32[K][C] -> bf16[C][K]
__global__ __launch_bounds__(256) void wt_k(const float* __restrict__ cw1, const float* __restrict__ cw2,
                                            const float* __restrict__ aiw, const float* __restrict__ aow,
                                            const float* __restrict__ mw1, const float* __restrict__ mw2) {
    __shared__ float t[64][65];
    int b = blockIdx.x;
    int l = b / 160, r = b % 160;
    const float* src; int ldw, ldk, ctiles; size_t doff;
    if (r < 16)      { src = cw1 + (size_t)l * 65536;  ldw = 256; ldk = 256; ctiles = 4;  doff = 0;      }
    else if (r < 32) { src = cw2 + (size_t)l * 65536;  ldw = 256; ldk = 256; ctiles = 4;  doff = 65536;  r -= 16; }
    else if (r < 80) { src = aiw + (size_t)l * 196608; ldw = 768; ldk = 256; ctiles = 12; doff = 131072; r -= 32; }
    else if (r < 96) { src = aow + (size_t)l * 65536;  ldw = 256; ldk = 256; ctiles = 4;  doff = 327680; r -= 80; }
    else if (r < 128){ src = mw1 + (size_t)l * 131072; ldw = 512; ldk = 256; ctiles = 8;  doff = 393216; r -= 96; }
    else             { src = mw2 + (size_t)l * 131072; ldw = 256; ldk = 512; ctiles = 4;  doff = 524288; r -= 128; }
    int kt = r / ctiles, ct = r % ctiles;
    int k0 = kt * 64, c0 = ct * 64;
    US* dst = g_wt + (size_t)l * 655360 + doff;
    int tid = threadIdx.x;
    int rr = tid >> 4, c4 = (tid & 15) * 4;
    #pragma unroll
    for (int j = 0; j < 4; j++) {
        float4 v = *(const float4*)(src + (size_t)(k0 + rr + j * 16) * ldw + c0 + c4);
        t[rr + j * 16][c4 + 0] = v.x; t[rr + j * 16][c4 + 1] = v.y;
        t[rr + j * 16][c4 + 2] = v.z; t[rr + j * 16][c4 + 3] = v.w;
    }
    __syncthreads();
    #pragma unroll
    for (int j = 0; j < 4; j++) {
        int crow = rr + j * 16;
        ushort4 o;
        o.x = f2b(t[c4 + 0][crow]); o.y = f2b(t[c4 + 1][crow]);
        o.z = f2b(t[c4 + 2][crow]); o.w = f2b(t[c4 + 3][crow]);
        *(ushort4*)(dst + (size_t)(c0 + crow) * ldk + k0 + c4) = o;
    }
}

// ---------------------------------------------------------------- CSR build (once per launch)
__global__ __launch_bounds__(256) void csr_k(const int* __restrict__ ei,
                                             const int* __restrict__ attr) {
    __shared__ int deg[64], off[65];
    int g = blockIdx.x, tid = threadIdx.x;
    if (tid < 64) deg[tid] = 0;
    __syncthreads();
    int e = g * 256 + tid;
    int d = ei[N_EDGES + e] - g * 64;
    int slot = atomicAdd(&deg[d], 1);
    __syncthreads();
    if (tid == 0) {
        off[0] = 0;
        for (int i = 0; i < 64; i++) off[i + 1] = off[i] + deg[i];
    }
    __syncthreads();
    g_csr[g * 256 + off[d] + slot] = (ei[e] - g * 64) | (attr[e] << 6);
    if (tid < 65) g_off[g * 65 + tid] = off[tid];
}

// ---------------------------------------------------------------- pe stats (2-stage)
__global__ __launch_bounds__(256) void pe_part_k(const float* __restrict__ pe) {
    __shared__ float red[240], red2[240];
    int b = blockIdx.x, tid = threadIdx.x;
    float s = 0.f, s2 = 0.f;
    if (tid < 240) {
        int ch = tid % 20, sub = tid / 20;
        size_t r0 = (size_t)b * 512;
        for (int r = sub; r < 512; r += 12) {
            float v = pe[(r0 + r) * 20 + ch];
            s += v; s2 += v * v;
        }
        red[tid] = s; red2[tid] = s2;
    }
    __syncthreads();
    if (tid < 20) {
        float ts = 0.f, ts2 = 0.f;
        #pragma unroll
        for (int sub = 0; sub < 12; sub++) { ts += red[sub * 20 + tid]; ts2 += red2[sub * 20 + tid]; }
        atomicAdd(&g_pe[tid], ts);
        atomicAdd(&g_pe[20 + tid], ts2);
    }
}

__global__ __launch_bounds__(64) void pe_fin_k(const float* __restrict__ g,
                                               const float* __restrict__ b) {
    int t = threadIdx.x;
    if (t < 20) {
        float mean = g_pe[t] / (float)N_NODES;
        float var  = g_pe[20 + t] / (float)N_NODES - mean * mean;
        float a = g[t] * rsqrtf(var + 1e-5f);
        g_peaff[t] = a;
        g_peaff[20 + t] = b[t] - mean * a;
        g_pe[t] = 0.f;          // re-zero for deterministic replay
        g_pe[20 + t] = 0.f;
    }
}

// ---------------------------------------------------------------- embed
__global__ __launch_bounds__(256) void embed_k(const int* __restrict__ x,
                                               const float* __restrict__ pe,
                                               const float* __restrict__ node_emb,
                                               const float* __restrict__ plw,
                                               const float* __restrict__ plb,
                                               US* __restrict__ h) {
    int n = blockIdx.x;
    int tid = threadIdx.x;
    int xi = x[n];
    float v;
    if (tid < 192) {
        v = node_emb[xi * 192 + tid];
    } else {
        int j = tid - 192;
        float s = plb[j];
        #pragma unroll
        for (int k = 0; k < 20; k++) {
            float p = pe[(size_t)n * 20 + k] * g_peaff[k] + g_peaff[20 + k];
            s += p * plw[k * 64 + j];
        }
        v = s;
    }
    h[(size_t)n * CCH + tid] = f2b(v);
}

// ---------------------------------------------------------------- edge aggregation: CSR, no atomics
__global__ __launch_bounds__(256) void aggr_z_k(const US* __restrict__ h,
                                                const float* __restrict__ eemb,
                                                US* __restrict__ z) {
    __shared__ US ht[64 * 264];
    __shared__ float em[4 * 260];
    __shared__ int off[65], ce[256];
    int g = blockIdx.x, tid = threadIdx.x;
    for (int v = tid; v < 2048; v += 256) {
        int row = v >> 5, seg = (v & 31) * 8;
        *(v8us*)&ht[row * 264 + seg] = *(const v8us*)(h + (size_t)(g * 64 + row) * 256 + seg);
    }
    for (int i = tid; i < 1024; i += 256)
        em[(i >> 8) * 260 + (i & 255)] = eemb[(i >> 8) * 256 + (i & 255)];
    ce[tid] = g_csr[g * 256 + tid];
    if (tid < 65) off[tid] = g_off[g * 65 + tid];
    __syncthreads();

    int dst = tid >> 2, cq = (tid & 3) * 4;
    float acc[64];
    #pragma unroll
    for (int i = 0; i < 64; i++) acc[i] = 0.f;
    int e1 = off[dst + 1];
    for (int e = off[dst]; e < e1; e++) {
        int val = ce[e];
        int src = val & 63, a = (val >> 6) & 3;
        #pragma unroll
        for (int i = 0; i < 16; i++) {
            int c = cq + i * 16;
            ushort4 hv = *(ushort4*)&ht[src * 264 + c];
            float4 ev = *(float4*)&em[a * 260 + c];
            acc[i * 4 + 0] += fmaxf(b2f(hv.x) + ev.x, 0.f);
            acc[i * 4 + 1] += fmaxf(b2f(hv.y) + ev.y, 0.f);
            acc[i * 4 + 2] += fmaxf(b2f(hv.z) + ev.z, 0.f);
            acc[i * 4 + 3] += fmaxf(b2f(hv.w) + ev.w, 0.f);
        }
    }
    US* zp = z + (size_t)(g * 64 + dst) * 256;
    #pragma unroll
    for (int i = 0; i < 16; i++) {
        int c = cq + i * 16;
        ushort4 hv = *(ushort4*)&ht[dst * 264 + c];
        ushort4 o;
        o.x = f2b(b2f(hv.x) + acc[i * 4 + 0]);
        o.y = f2b(b2f(hv.y) + acc[i * 4 + 1]);
        o.z = f2b(b2f(hv.z) + acc[i * 4 + 2]);
        o.w = f2b(b2f(hv.w) + acc[i * 4 + 3]);
        *(ushort4*)(zp + c) = o;
    }
}

// ---------------------------------------------------------------- MFMA bf16 GEMM, NG 64-col groups per block
// Block = 128 rows x NG*64 cols. W col base per group g: wsel(g). Output buffer cols 0..NG*64.
// mode 0 none, 1 relu, 2 +=res
template<int NG>
__global__ __launch_bounds__(256, 2) void gemm_mfma_k(const US* __restrict__ A,
                                                      size_t woff, int ldk,
                                                      int w0, int w1, int w2, int w3,
                                                      const float* __restrict__ bias,
                                                      const US* __restrict__ res,
                                                      US* __restrict__ Y, int mode) {
    const US* __restrict__ Wt = g_wt + woff;
    __shared__ __align__(16) US As[128 * 40];
    __shared__ __align__(16) US Bs[NG * 64 * 40];
    int tid = threadIdx.x;
    size_t row0 = (size_t)blockIdx.x * 128;
    int w = tid >> 6, l = tid & 63;

    int a_off0 = (w * 32 + (l & 15)) * 40 + (l >> 4) * 8;
    int a_off1 = a_off0 + 16 * 40;
    int b_off  = (l & 15) * 40 + (l >> 4) * 8;
    int sb_c = tid >> 2, sb_ko = (tid & 3) * 8;

    v4f acc[2][NG * 4];
    #pragma unroll
    for (int i = 0; i < 2; i++)
        #pragma unroll
        for (int t = 0; t < NG * 4; t++) acc[i][t] = (v4f){0.f, 0.f, 0.f, 0.f};

    for (int k0 = 0; k0 < 256; k0 += 32) {
        #pragma unroll
        for (int p = 0; p < 2; p++) {
            int cidx = tid + p * 256;
            int row = cidx >> 2, ko = (cidx & 3) * 8;
            *(v8us*)&As[row * 40 + ko] = *(const v8us*)(A + (row0 + row) * 256 + k0 + ko);
        }
        #pragma unroll
        for (int p = 0; p < NG; p++) {          // group index == p (cols p*64 + tid>>2)
            int wb = (p == 0) ? w0 : (p == 1) ? w1 : (p == 2) ? w2 : w3;
            *(v8us*)&Bs[(p * 64 + sb_c) * 40 + sb_ko] =
                *(const v8us*)(Wt + (size_t)(wb + sb_c) * ldk + k0 + sb_ko);
        }
        __syncthreads();
        v8s a0 = *(v8s*)&As[a_off0];
        v8s a1 = *(v8s*)&As[a_off1];
        #pragma unroll
        for (int t = 0; t < NG * 4; t++) {
            v8s bf = *(v8s*)&Bs[b_off + t * 640];
            acc[0][t] = __builtin_amdgcn_mfma_f32_16x16x32_bf16(a0, bf, acc[0][t], 0, 0, 0);
            acc[1][t] = __builtin_amdgcn_mfma_f32_16x16x32_bf16(a1, bf, acc[1][t], 0, 0, 0);
        }
        __syncthreads();
    }
    int col_l = l & 15;
    int rs = (l >> 4) * 4;
    #pragma unroll
    for (int i = 0; i < 2; i++) {
        #pragma unroll
        for (int t = 0; t < NG * 4; t++) {
            int grp = t >> 2;
            int wb = (grp == 0) ? w0 : (grp == 1) ? w1 : (grp == 2) ? w2 : w3;
            int c = t * 16 + col_l;
            float bv = bias ? bias[wb + (t & 3) * 16 + col_l] : 0.f;
            #pragma unroll
            for (int r = 0; r < 4; r++) {
                size_t rr = row0 + w * 32 + i * 16 + rs + r;
                float v = acc[i][t][r] + bv;
                if (mode == 1) v = fmaxf(v, 0.f);
                if (mode == 2) v += b2f(res[rr * 256 + c]);
                Y[rr * 256 + c] = f2b(v);
            }
        }
    }
}

// ---------------------------------------------------------------- MFMA attention: 1 wave = (graph, head)
// qkv packed in A cols: q 0..63, k 64..127, v 128..191. o pre-offset to head col block.
__global__ __launch_bounds__(64) void attn_k(const US* __restrict__ qkv,
                                             US* __restrict__ o) {
    __shared__ __align__(16) US Ps[64 * 72];   // P (then O) tile
    __shared__ __align__(16) US Vt[64 * 72];   // V transposed [d][k]
    int g = blockIdx.x, l = threadIdx.x;
    int li = l & 15, hi8 = (l >> 4) * 8, hi4 = (l >> 4) * 4;
    const US* base = qkv + (size_t)g * 64 * 256;

    // stage V transposed: thread l owns V row l (k=l), writes Vt[d][l]
    {
        v8us vv[8];
        #pragma unroll
        for (int jv = 0; jv < 8; jv++)
            vv[jv] = *(const v8us*)(base + l * 256 + 128 + jv * 8);
        #pragma unroll
        for (int jv = 0; jv < 8; jv++)
            #pragma unroll
            for (int e = 0; e < 8; e++)
                Vt[(jv * 8 + e) * 72 + l] = vv[jv][e];
    }

    // Q/K fragments straight from global (L2-hot)
    v8s Qf[4][2], Kf[4][2];
    #pragma unroll
    for (int t = 0; t < 4; t++)
        #pragma unroll
        for (int ds = 0; ds < 2; ds++) {
            Qf[t][ds] = *(const v8s*)(base + (t * 16 + li) * 256 + ds * 32 + hi8);
            Kf[t][ds] = *(const v8s*)(base + (t * 16 + li) * 256 + 64 + ds * 32 + hi8);
        }

    // S = Q K^T  (4x4 tiles)
    v4f S[4][4];
    #pragma unroll
    for (int qt = 0; qt < 4; qt++)
        #pragma unroll
        for (int kt = 0; kt < 4; kt++) {
            v4f a = (v4f){0.f, 0.f, 0.f, 0.f};
            a = __builtin_amdgcn_mfma_f32_16x16x32_bf16(Qf[qt][0], Kf[kt][0], a, 0, 0, 0);
            a = __builtin_amdgcn_mfma_f32_16x16x32_bf16(Qf[qt][1], Kf[kt][1], a, 0, 0, 0);
            S[qt][kt] = a;
        }

    // softmax rows (row = qt*16 + hi4 + r; cols spread over li and kt)
    #pragma unroll
    for (int qt = 0; qt < 4; qt++)
        #pragma unroll
        for (int r = 0; r < 4; r++) {
            float mx = -1e30f;
            #pragma unroll
            for (int kt = 0; kt < 4; kt++) {
                S[qt][kt][r] *= 0.125f;
                mx = fmaxf(mx, S[qt][kt][r]);
            }
            mx = fmaxf(mx, __shfl_xor(mx, 1));
            mx = fmaxf(mx, __shfl_xor(mx, 2));
            mx = fmaxf(mx, __shfl_xor(mx, 4));
            mx = fmaxf(mx, __shfl_xor(mx, 8));
            float sum = 0.f;
            #pragma unroll
            for (int kt = 0; kt < 4; kt++) {
                float e = __expf(S[qt][kt][r] - mx);
                S[qt][kt][r] = e;
                sum += e;
            }
            sum += __shfl_xor(sum, 1);
            sum += __shfl_xor(sum, 2);
            sum += __shfl_xor(sum, 4);
            sum += __shfl_xor(sum, 8);
            float inv = 1.f / sum;
            #pragma unroll
            for (int kt = 0; kt < 4; kt++)
                Ps[(qt * 16 + hi4 + r) * 72 + kt * 16 + li] = f2b(S[qt][kt][r] * inv);
        }

    // O = P V   (4 qt x 4 jt tiles, k=64 in 2 steps)
    v4f O[4][4];
    #pragma unroll
    for (int qt = 0; qt < 4; qt++)
        #pragma unroll
        for (int jt = 0; jt < 4; jt++) O[qt][jt] = (v4f){0.f, 0.f, 0.f, 0.f};
    #pragma unroll
    for (int ks = 0; ks < 2; ks++) {
        v8s Pf[4], Vf[4];
        #pragma unroll
        for (int qt = 0; qt < 4; qt++)
            Pf[qt] = *(v8s*)&Ps[(qt * 16 + li) * 72 + ks * 32 + hi8];
        #pragma unroll
        for (int jt = 0; jt < 4; jt++)
            Vf[jt] = *(v8s*)&Vt[(jt * 16 + li) * 72 + ks * 32 + hi8];
        #pragma unroll
        for (int qt = 0; qt < 4; qt++)
            #pragma unroll
            for (int jt = 0; jt < 4; jt++)
                O[qt][jt] = __builtin_amdgcn_mfma_f32_16x16x32_bf16(Pf[qt], Vf[jt], O[qt][jt], 0, 0, 0);
    }

    // O -> LDS (reuse Ps) -> coalesced global stores
    #pragma unroll
    for (int qt = 0; qt < 4; qt++)
        #pragma unroll
        for (int jt = 0; jt < 4; jt++)
            #pragma unroll
            for (int r = 0; r < 4; r++)
                Ps[(qt * 16 + hi4 + r) * 72 + jt * 16 + li] = f2b(O[qt][jt][r]);
    US* ob = o + (size_t)(g * 64 + l) * 256;
    #pragma unroll
    for (int jv = 0; jv < 8; jv++)
        *(v8us*)(ob + jv * 8) = *(v8us*)&Ps[l * 72 + jv * 8];
}

// ---------------------------------------------------------------- BN stats / affine
__global__ __launch_bounds__(256) void stats_k(const US* __restrict__ Y) {
    int c = threadIdx.x;
    size_t r0 = (size_t)blockIdx.x * 1024;
    float s = 0.f, s2 = 0.f;
    for (int r = 0; r < 1024; r++) {
        float v = b2f(Y[(r0 + r) * CCH + c]);
        s += v; s2 += v * v;
    }
    atomicAdd(&g_stats[c], s);
    atomicAdd(&g_stats[CCH + c], s2);
}

__global__ __launch_bounds__(256) void affine_k(const float* __restrict__ g,
                                                const float* __restrict__ b, int sel) {
    int c = threadIdx.x;
    float mean = g_stats[c] / (float)N_NODES;
    float var  = g_stats[CCH + c] / (float)N_NODES - mean * mean;
    float a = g[c] * rsqrtf(var + 1e-5f);
    float* dst = (sel == 0) ? g_aff1 : (sel == 1) ? g_aff2 : g_aff3;
    dst[c] = a;
    dst[CCH + c] = b[c] - mean * a;
    g_stats[c] = 0.f;
    g_stats[CCH + c] = 0.f;
}

// ---------------------------------------------------------------- elementwise (v8us vectorized)
__global__ __launch_bounds__(256) void combine_k(const US* __restrict__ y1,
                                                 const US* __restrict__ y2,
                                                 US* __restrict__ out) {
    size_t idx = (size_t)blockIdx.x * 256 + threadIdx.x;
    size_t stride = (size_t)gridDim.x * 256;
    for (; idx < (size_t)N_NODES * CCH / 8; idx += stride) {
        size_t i = idx * 8;
        int c = (int)(i & 255);
        v8us a = *(const v8us*)(y1 + i);
        v8us b = *(const v8us*)(y2 + i);
        v8us o;
        #pragma unroll
        for (int j = 0; j < 8; j++) {
            float v = b2f(a[j]) * g_aff1[c + j] + g_aff1[CCH + c + j] +
                      b2f(b[j]) * g_aff2[c + j] + g_aff2[CCH + c + j];
            o[j] = f2b(v);
        }
        *(v8us*)(out + i) = o;
    }
}

__global__ __launch_bounds__(256) void apply_k(US* __restrict__ h) {
    size_t idx = (size_t)blockIdx.x * 256 + threadIdx.x;
    size_t stride = (size_t)gridDim.x * 256;
    for (; idx < (size_t)N_NODES * CCH / 8; idx += stride) {
        size_t i = idx * 8;
        int c = (int)(i & 255);
        v8us a = *(const v8us*)(h + i);
        v8us o;
        #pragma unroll
        for (int j = 0; j < 8; j++)
            o[j] = f2b(b2f(a[j]) * g_aff3[c + j] + g_aff3[CCH + c + j]);
        *(v8us*)(h + i) = o;
    }
}

// ---------------------------------------------------------------- pool + head
__global__ __launch_bounds__(256) void pool_k(const US* __restrict__ h,
                                              float* __restrict__ pooled) {
    int g = blockIdx.x, c = threadIdx.x;
    float s = 0.f;
    for (int ss = 0; ss < SEQ; ss++) s += b2f(h[((size_t)g * SEQ + ss) * CCH + c]);
    pooled[(size_t)g * CCH + c] = s;
}

__global__ __launch_bounds__(128) void head_k(const float* __restrict__ pooled,
                                              const float* __restrict__ w1, const float* __restrict__ b1,
                                              const float* __restrict__ w2, const float* __restrict__ b2,
                                              const float* __restrict__ w3, const float* __restrict__ b3,
                                              float* __restrict__ outp) {
    __shared__ float p[256], t1[128], t2[64];
    int g = blockIdx.x, tid = threadIdx.x;
    p[tid] = pooled[(size_t)g * CCH + tid];
    p[tid + 128] = pooled[(size_t)g * CCH + 128 + tid];
    __syncthreads();
    float s = b1[tid];
    for (int k = 0; k < 256; k++) s += p[k] * w1[k * 128 + tid];
    t1[tid] = fmaxf(s, 0.f);
    __syncthreads();
    if (tid < 64) {
        float s2 = b2[tid];
        for (int k = 0; k < 128; k++) s2 += t1[k] * w2[k * 64 + tid];
        t2[tid] = fmaxf(s2, 0.f);
    }
    __syncthreads();
    if (tid == 0) {
        float s3 = b3[0];
        for (int k = 0; k < 64; k++) s3 += t2[k] * w3[k];
        outp[g] = s3;
    }
}

// ================================================================ launch
extern "C" void kernel_launch(void* const* d_in, const int* in_sizes, int n_in,
                              void* d_out, int out_size, void* d_ws, size_t ws_size,
                              hipStream_t stream) {
    const int*   x         = (const int*)  d_in[0];
    const float* pe        = (const float*)d_in[1];
    const int*   ei        = (const int*)  d_in[2];
    const int*   eattr     = (const int*)  d_in[3];
    const float* node_emb  = (const float*)d_in[5];
    const float* pe_lin_w  = (const float*)d_in[6];
    const float* pe_lin_b  = (const float*)d_in[7];
    const float* pe_norm_g = (const float*)d_in[8];
    const float* pe_norm_b = (const float*)d_in[9];
    const float* edge_emb  = (const float*)d_in[10];
    const float* conv_w1   = (const float*)d_in[11];
    const float* conv_b1   = (const float*)d_in[12];
    const float* conv_w2   = (const float*)d_in[13];
    const float* conv_b2   = (const float*)d_in[14];
    const float* attn_in_w = (const float*)d_in[15];
    const float* attn_in_b = (const float*)d_in[16];
    const float* attn_out_w= (const float*)d_in[17];
    const float* attn_out_b= (const float*)d_in[18];
    const float* bn1_g     = (const float*)d_in[19];
    const float* bn1_b     = (const float*)d_in[20];
    const float* bn2_g     = (const float*)d_in[21];
    const float* bn2_b     = (const float*)d_in[22];
    const float* bn3_g     = (const float*)d_in[23];
    const float* bn3_b     = (const float*)d_in[24];
    const float* mlp_w1    = (const float*)d_in[25];
    const float* mlp_b1    = (const float*)d_in[26];
    const float* mlp_w2    = (const float*)d_in[27];
    const float* mlp_b2    = (const float*)d_in[28];
    const float* head_w1   = (const float*)d_in[29];
    const float* head_b1   = (const float*)d_in[30];
    const float* head_w2   = (const float*)d_in[31];
    const float* head_b2   = (const float*)d_in[32];
    const float* head_w3   = (const float*)d_in[33];
    const float* head_b3   = (const float*)d_in[34];
    (void)in_sizes; (void)n_in; (void)out_size; (void)ws_size;

    // workspace: 4 x 64 MB bf16 [N,256] buffers = 256 MB total (proven safe)
    char* ws = (char*)d_ws;
    US* h = (US*)(ws);
    US* A = (US*)(ws + 67108864ULL);
    US* B = (US*)(ws + 134217728ULL);
    US* C = (US*)(ws + 201326592ULL);
    float* pooled = (float*)(ws + 67108864ULL);   // reuses A (dead after layer loop)

    wt_k<<<960, 256, 0, stream>>>(conv_w1, conv_w2, attn_in_w, attn_out_w, mlp_w1, mlp_w2);
    csr_k<<<N_GRAPHS_, 256, 0, stream>>>(ei, eattr);
    pe_part_k<<<256, 256, 0, stream>>>(pe);
    pe_fin_k<<<1, 64, 0, stream>>>(pe_norm_g, pe_norm_b);
    embed_k<<<N_NODES, 256, 0, stream>>>(x, pe, node_emb, pe_lin_w, pe_lin_b, h);

    for (int l = 0; l < LAYERS; l++) {
        size_t wl = (size_t)l * 655360;

        // ---- local GINEConv ----
        aggr_z_k<<<N_GRAPHS_, 256, 0, stream>>>(h, edge_emb, A);                        // z=A
        gemm_mfma_k<4><<<1024, 256, 0, stream>>>(A, wl, 256, 0, 64, 128, 192,
                                                 conv_b1 + l * 256, nullptr, B, 1);     // t1
        gemm_mfma_k<4><<<1024, 256, 0, stream>>>(B, wl + 65536, 256, 0, 64, 128, 192,
                                                 conv_b2 + l * 256, h, C, 2);           // y1
        stats_k<<<128, 256, 0, stream>>>(C);
        affine_k<<<1, 256, 0, stream>>>(bn1_g + l * 256, bn1_b + l * 256, 0);

        // ---- global attention (per head; q|k|v in A cols 0..191, o in B col blocks) ----
        for (int hh = 0; hh < 4; hh++) {
            gemm_mfma_k<3><<<1024, 256, 0, stream>>>(h, wl + 131072, 256,
                                                     hh * 64, 256 + hh * 64, 512 + hh * 64, 0,
                                                     attn_in_b + l * 768, nullptr, A, 0);
            attn_k<<<N_GRAPHS_, 64, 0, stream>>>(A, B + hh * 64);
        }
        gemm_mfma_k<4><<<1024, 256, 0, stream>>>(B, wl + 327680, 256, 0, 64, 128, 192,
                                                 attn_out_b + l * 256, h, h, 2);        // y2->h
        stats_k<<<128, 256, 0, stream>>>(h);
        affine_k<<<1, 256, 0, stream>>>(bn2_g + l * 256, bn2_b + l * 256, 1);

        // ---- combine + FFN (512-wide hidden in two 256 halves) ----
        combine_k<<<2048, 256, 0, stream>>>(C, h, A);                                   // out=A
        gemm_mfma_k<4><<<1024, 256, 0, stream>>>(A, wl + 393216, 256, 0, 64, 128, 192,
                                                 mlp_b1 + l * 512, nullptr, B, 1);      // tA
        gemm_mfma_k<4><<<1024, 256, 0, stream>>>(B, wl + 524288, 512, 0, 64, 128, 192,
                                                 mlp_b2 + l * 256, A, C, 2);            // partial
        gemm_mfma_k<4><<<1024, 256, 0, stream>>>(A, wl + 393216, 256, 256, 320, 384, 448,
                                                 mlp_b1 + l * 512, nullptr, B, 1);      // tB
        gemm_mfma_k<4><<<1024, 256, 0, stream>>>(B, wl + 524288 + 256, 512, 0, 64, 128, 192,
                                                 nullptr, C, h, 2);                     // y3->h
        stats_k<<<128, 256, 0, stream>>>(h);
        affine_k<<<1, 256, 0, stream>>>(bn3_g + l * 256, bn3_b + l * 256, 2);
        apply_k<<<2048, 256, 0, stream>>>(h);
    }

    pool_k<<<N_GRAPHS_, 256, 0, stream>>>(h, pooled);
    head_k<<<N_GRAPHS_, 128, 0, stream>>>(pooled, head_w1, head_b1, head_w2, head_b2,
                                          head_w3, head_b3, (float*)d_out);
}

// Round 8
// 5742.945 us; speedup vs baseline: 3.6664x; 1.0600x over previous
//
#include <hip/hip_runtime.h>

#define N_NODES 131072
#define N_EDGES 524288
#define CCH 256
#define N_GRAPHS_ 2048
#define SEQ 64
#define LAYERS 6

typedef unsigned short US;
typedef __attribute__((ext_vector_type(8))) short v8s;           // MFMA bf16 frag
typedef __attribute__((ext_vector_type(8))) unsigned short v8us; // 16B ushort vector
typedef __attribute__((ext_vector_type(4))) float v4f;           // MFMA f32 acc

__device__ __forceinline__ float b2f(US u) { return __uint_as_float(((unsigned)u) << 16); }
__device__ __forceinline__ US f2b(float f) {
    unsigned u = __float_as_uint(f);
    return (US)((u + 0x7fff + ((u >> 16) & 1)) >> 16);   // RNE
}

// cross-kernel state — referenced ONLY inside device code (never from host!)
__device__ float g_stats[512];
__device__ float g_aff1[512];
__device__ float g_aff2[512];
__device__ float g_aff3[512];
__device__ float g_pe[40];
__device__ float g_peaff[40];
__device__ US    g_wt[6 * 655360];          // per-layer transposed bf16 weights
__device__ int   g_csr[N_EDGES];            // per-graph dst-sorted edges: srcLocal | attr<<6
__device__ int   g_off[N_GRAPHS_ * 65];     // per-graph CSR offsets

// ---------------------------------------------------------------- weight transpose f32[K][C] -> bf16[C][K]
__global__ __launch_bounds__(256) void wt_k(const float* __restrict__ cw1, const float* __restrict__ cw2,
                                            const float* __restrict__ aiw, const float* __restrict__ aow,
                                            const float* __restrict__ mw1, const float* __restrict__ mw2) {
    __shared__ float t[64][65];
    int b = blockIdx.x;
    int l = b / 160, r = b % 160;
    const float* src; int ldw, ldk, ctiles; size_t doff;
    if (r < 16)      { src = cw1 + (size_t)l * 65536;  ldw = 256; ldk = 256; ctiles = 4;  doff = 0;      }
    else if (r < 32) { src = cw2 + (size_t)l * 65536;  ldw = 256; ldk = 256; ctiles = 4;  doff = 65536;  r -= 16; }
    else if (r < 80) { src = aiw + (size_t)l * 196608; ldw = 768; ldk = 256; ctiles = 12; doff = 131072; r -= 32; }
    else if (r < 96) { src = aow + (size_t)l * 65536;  ldw = 256; ldk = 256; ctiles = 4;  doff = 327680; r -= 80; }
    else if (r < 128){ src = mw1 + (size_t)l * 131072; ldw = 512; ldk = 256; ctiles = 8;  doff = 393216; r -= 96; }
    else             { src = mw2 + (size_t)l * 131072; ldw = 256; ldk = 512; ctiles = 4;  doff = 524288; r -= 128; }
    int kt = r / ctiles, ct = r % ctiles;
    int k0 = kt * 64, c0 = ct * 64;
    US* dst = g_wt + (size_t)l * 655360 + doff;
    int tid = threadIdx.x;
    int rr = tid >> 4, c4 = (tid & 15) * 4;
    #pragma unroll
    for (int j = 0; j < 4; j++) {
        float4 v = *(const float4*)(src + (size_t)(k0 + rr + j * 16) * ldw + c0 + c4);
        t[rr + j * 16][c4 + 0] = v.x; t[rr + j * 16][c4 + 1] = v.y;
        t[rr + j * 16][c4 + 2] = v.z; t[rr + j * 16][c4 + 3] = v.w;
    }
    __syncthreads();
    #pragma unroll
    for (int j = 0; j < 4; j++) {
        int crow = rr + j * 16;
        ushort4 o;
        o.x = f2b(t[c4 + 0][crow]); o.y = f2b(t[c4 + 1][crow]);
        o.z = f2b(t[c4 + 2][crow]); o.w = f2b(t[c4 + 3][crow]);
        *(ushort4*)(dst + (size_t)(c0 + crow) * ldk + k0 + c4) = o;
    }
}

// ---------------------------------------------------------------- CSR build (once per launch)
__global__ __launch_bounds__(256) void csr_k(const int* __restrict__ ei,
                                             const int* __restrict__ attr) {
    __shared__ int deg[64], off[65];
    int g = blockIdx.x, tid = threadIdx.x;
    if (tid < 64) deg[tid] = 0;
    __syncthreads();
    int e = g * 256 + tid;
    int d = ei[N_EDGES + e] - g * 64;
    int slot = atomicAdd(&deg[d], 1);
    __syncthreads();
    if (tid == 0) {
        off[0] = 0;
        for (int i = 0; i < 64; i++) off[i + 1] = off[i] + deg[i];
    }
    __syncthreads();
    g_csr[g * 256 + off[d] + slot] = (ei[e] - g * 64) | (attr[e] << 6);
    if (tid < 65) g_off[g * 65 + tid] = off[tid];
}

// ---------------------------------------------------------------- pe stats (2-stage)
__global__ __launch_bounds__(256) void pe_part_k(const float* __restrict__ pe) {
    __shared__ float red[240], red2[240];
    int b = blockIdx.x, tid = threadIdx.x;
    float s = 0.f, s2 = 0.f;
    if (tid < 240) {
        int ch = tid % 20, sub = tid / 20;
        size_t r0 = (size_t)b * 512;
        for (int r = sub; r < 512; r += 12) {
            float v = pe[(r0 + r) * 20 + ch];
            s += v; s2 += v * v;
        }
        red[tid] = s; red2[tid] = s2;
    }
    __syncthreads();
    if (tid < 20) {
        float ts = 0.f, ts2 = 0.f;
        #pragma unroll
        for (int sub = 0; sub < 12; sub++) { ts += red[sub * 20 + tid]; ts2 += red2[sub * 20 + tid]; }
        atomicAdd(&g_pe[tid], ts);
        atomicAdd(&g_pe[20 + tid], ts2);
    }
}

__global__ __launch_bounds__(64) void pe_fin_k(const float* __restrict__ g,
                                               const float* __restrict__ b) {
    int t = threadIdx.x;
    if (t < 20) {
        float mean = g_pe[t] / (float)N_NODES;
        float var  = g_pe[20 + t] / (float)N_NODES - mean * mean;
        float a = g[t] * rsqrtf(var + 1e-5f);
        g_peaff[t] = a;
        g_peaff[20 + t] = b[t] - mean * a;
        g_pe[t] = 0.f;          // re-zero for deterministic replay
        g_pe[20 + t] = 0.f;
    }
}

// ---------------------------------------------------------------- embed
__global__ __launch_bounds__(256) void embed_k(const int* __restrict__ x,
                                               const float* __restrict__ pe,
                                               const float* __restrict__ node_emb,
                                               const float* __restrict__ plw,
                                               const float* __restrict__ plb,
                                               US* __restrict__ h) {
    int n = blockIdx.x;
    int tid = threadIdx.x;
    int xi = x[n];
    float v;
    if (tid < 192) {
        v = node_emb[xi * 192 + tid];
    } else {
        int j = tid - 192;
        float s = plb[j];
        #pragma unroll
        for (int k = 0; k < 20; k++) {
            float p = pe[(size_t)n * 20 + k] * g_peaff[k] + g_peaff[20 + k];
            s += p * plw[k * 64 + j];
        }
        v = s;
    }
    h[(size_t)n * CCH + tid] = f2b(v);
}

// ---------------------------------------------------------------- edge aggregation: CSR, no atomics
__global__ __launch_bounds__(256) void aggr_z_k(const US* __restrict__ h,
                                                const float* __restrict__ eemb,
                                                US* __restrict__ z) {
    __shared__ US ht[64 * 264];
    __shared__ float em[4 * 260];
    __shared__ int off[65], ce[256];
    int g = blockIdx.x, tid = threadIdx.x;
    for (int v = tid; v < 2048; v += 256) {
        int row = v >> 5, seg = (v & 31) * 8;
        *(v8us*)&ht[row * 264 + seg] = *(const v8us*)(h + (size_t)(g * 64 + row) * 256 + seg);
    }
    for (int i = tid; i < 1024; i += 256)
        em[(i >> 8) * 260 + (i & 255)] = eemb[(i >> 8) * 256 + (i & 255)];
    ce[tid] = g_csr[g * 256 + tid];
    if (tid < 65) off[tid] = g_off[g * 65 + tid];
    __syncthreads();

    int dst = tid >> 2, cq = (tid & 3) * 4;
    float acc[64];
    #pragma unroll
    for (int i = 0; i < 64; i++) acc[i] = 0.f;
    int e1 = off[dst + 1];
    for (int e = off[dst]; e < e1; e++) {
        int val = ce[e];
        int src = val & 63, a = (val >> 6) & 3;
        #pragma unroll
        for (int i = 0; i < 16; i++) {
            int c = cq + i * 16;
            ushort4 hv = *(ushort4*)&ht[src * 264 + c];
            float4 ev = *(float4*)&em[a * 260 + c];
            acc[i * 4 + 0] += fmaxf(b2f(hv.x) + ev.x, 0.f);
            acc[i * 4 + 1] += fmaxf(b2f(hv.y) + ev.y, 0.f);
            acc[i * 4 + 2] += fmaxf(b2f(hv.z) + ev.z, 0.f);
            acc[i * 4 + 3] += fmaxf(b2f(hv.w) + ev.w, 0.f);
        }
    }
    US* zp = z + (size_t)(g * 64 + dst) * 256;
    #pragma unroll
    for (int i = 0; i < 16; i++) {
        int c = cq + i * 16;
        ushort4 hv = *(ushort4*)&ht[dst * 264 + c];
        ushort4 o;
        o.x = f2b(b2f(hv.x) + acc[i * 4 + 0]);
        o.y = f2b(b2f(hv.y) + acc[i * 4 + 1]);
        o.z = f2b(b2f(hv.z) + acc[i * 4 + 2]);
        o.w = f2b(b2f(hv.w) + acc[i * 4 + 3]);
        *(ushort4*)(zp + c) = o;
    }
}

// ---------------------------------------------------------------- MFMA bf16 GEMM, register-prefetch pipeline
// Block = 128 rows x NG*64 cols; W col base per group p = w0..w3.
// mode 0 none, 1 relu, 2 +=res. STATS: accumulate column (sum,sumsq) into g_stats.
template<int NG, bool STATS>
__global__ __launch_bounds__(256, 2) void gemm_mfma_k(const US* __restrict__ A,
                                                      size_t woff, int ldk,
                                                      int w0, int w1, int w2, int w3,
                                                      const float* __restrict__ bias,
                                                      const US* __restrict__ res,
                                                      US* __restrict__ Y, int mode) {
    const US* __restrict__ Wt = g_wt + woff;
    __shared__ __align__(16) US As[128 * 40];
    __shared__ __align__(16) US Bs[NG * 64 * 40];
    int tid = threadIdx.x;
    size_t row0 = (size_t)blockIdx.x * 128;
    int w = tid >> 6, l = tid & 63;

    int sb_c = tid >> 2, sb_ko = (tid & 3) * 8;
    int a_off0 = (w * 32 + (l & 15)) * 40 + (l >> 4) * 8;
    int a_off1 = a_off0 + 16 * 40;
    int b_off  = (l & 15) * 40 + (l >> 4) * 8;

    const US* aptr0 = A + (row0 + sb_c) * 256 + sb_ko;
    const US* aptr1 = aptr0 + 64 * 256;

    v4f acc[2][NG * 4];
    #pragma unroll
    for (int i = 0; i < 2; i++)
        #pragma unroll
        for (int t = 0; t < NG * 4; t++) acc[i][t] = (v4f){0.f, 0.f, 0.f, 0.f};

    // prefetch chunk 0
    v8us pa0 = *(const v8us*)aptr0;
    v8us pa1 = *(const v8us*)aptr1;
    v8us pb[NG];
    #pragma unroll
    for (int p = 0; p < NG; p++) {
        int wb = (p == 0) ? w0 : (p == 1) ? w1 : (p == 2) ? w2 : w3;
        pb[p] = *(const v8us*)(Wt + (size_t)(wb + sb_c) * ldk + sb_ko);
    }

    for (int kc = 0; kc < 8; kc++) {
        *(v8us*)&As[sb_c * 40 + sb_ko] = pa0;
        *(v8us*)&As[(sb_c + 64) * 40 + sb_ko] = pa1;
        #pragma unroll
        for (int p = 0; p < NG; p++)
            *(v8us*)&Bs[(p * 64 + sb_c) * 40 + sb_ko] = pb[p];
        __syncthreads();
        if (kc < 7) {                               // prefetch chunk kc+1 under this chunk's compute
            int kn = (kc + 1) * 32;
            pa0 = *(const v8us*)(aptr0 + kn);
            pa1 = *(const v8us*)(aptr1 + kn);
            #pragma unroll
            for (int p = 0; p < NG; p++) {
                int wb = (p == 0) ? w0 : (p == 1) ? w1 : (p == 2) ? w2 : w3;
                pb[p] = *(const v8us*)(Wt + (size_t)(wb + sb_c) * ldk + kn + sb_ko);
            }
        }
        v8s a0 = *(v8s*)&As[a_off0];
        v8s a1 = *(v8s*)&As[a_off1];
        #pragma unroll
        for (int t = 0; t < NG * 4; t++) {
            v8s bf = *(v8s*)&Bs[b_off + t * 640];
            acc[0][t] = __builtin_amdgcn_mfma_f32_16x16x32_bf16(a0, bf, acc[0][t], 0, 0, 0);
            acc[1][t] = __builtin_amdgcn_mfma_f32_16x16x32_bf16(a1, bf, acc[1][t], 0, 0, 0);
        }
        __syncthreads();
    }

    int col_l = l & 15;
    int rs = (l >> 4) * 4;
    float cs[NG * 4], cs2[NG * 4];
    if (STATS) {
        #pragma unroll
        for (int t = 0; t < NG * 4; t++) { cs[t] = 0.f; cs2[t] = 0.f; }
    }
    #pragma unroll
    for (int i = 0; i < 2; i++) {
        #pragma unroll
        for (int t = 0; t < NG * 4; t++) {
            int grp = t >> 2;
            int wb = (grp == 0) ? w0 : (grp == 1) ? w1 : (grp == 2) ? w2 : w3;
            int c = t * 16 + col_l;
            float bv = bias ? bias[wb + (t & 3) * 16 + col_l] : 0.f;
            #pragma unroll
            for (int r = 0; r < 4; r++) {
                size_t rr = row0 + w * 32 + i * 16 + rs + r;
                float v = acc[i][t][r] + bv;
                if (mode == 1) v = fmaxf(v, 0.f);
                if (mode == 2) v += b2f(res[rr * 256 + c]);
                if (STATS) { cs[t] += v; cs2[t] += v * v; }
                Y[rr * 256 + c] = f2b(v);
            }
        }
    }
    if (STATS) {
        // reduce over the 4 hi-groups within the wave -> lanes agree per (col_l, t)
        #pragma unroll
        for (int t = 0; t < NG * 4; t++) {
            cs[t]  += __shfl_xor(cs[t], 16);  cs[t]  += __shfl_xor(cs[t], 32);
            cs2[t] += __shfl_xor(cs2[t], 16); cs2[t] += __shfl_xor(cs2[t], 32);
        }
        float* sred = (float*)As;          // reuse As: [4 waves][256] x {s, s2} = 8 KB
        if ((l >> 4) == 0) {
            #pragma unroll
            for (int t = 0; t < NG * 4; t++) {
                sred[w * 256 + t * 16 + col_l] = cs[t];
                sred[1024 + w * 256 + t * 16 + col_l] = cs2[t];
            }
        }
        __syncthreads();
        int c = tid;
        if (c < NG * 64) {
            float s  = sred[c] + sred[256 + c] + sred[512 + c] + sred[768 + c];
            float s2 = sred[1024 + c] + sred[1280 + c] + sred[1536 + c] + sred[1792 + c];
            atomicAdd(&g_stats[c], s);
            atomicAdd(&g_stats[CCH + c], s2);
        }
    }
}

// ---------------------------------------------------------------- MFMA attention: 1 wave = (graph, head)
__global__ __launch_bounds__(64) void attn_k(const US* __restrict__ qkv,
                                             US* __restrict__ o) {
    __shared__ __align__(16) US Ps[64 * 72];   // P (then O) tile
    __shared__ __align__(16) US Vt[64 * 72];   // V transposed [d][k]
    int g = blockIdx.x, l = threadIdx.x;
    int li = l & 15, hi8 = (l >> 4) * 8, hi4 = (l >> 4) * 4;
    const US* base = qkv + (size_t)g * 64 * 256;

    {
        v8us vv[8];
        #pragma unroll
        for (int jv = 0; jv < 8; jv++)
            vv[jv] = *(const v8us*)(base + l * 256 + 128 + jv * 8);
        #pragma unroll
        for (int jv = 0; jv < 8; jv++)
            #pragma unroll
            for (int e = 0; e < 8; e++)
                Vt[(jv * 8 + e) * 72 + l] = vv[jv][e];
    }

    v8s Qf[4][2], Kf[4][2];
    #pragma unroll
    for (int t = 0; t < 4; t++)
        #pragma unroll
        for (int ds = 0; ds < 2; ds++) {
            Qf[t][ds] = *(const v8s*)(base + (t * 16 + li) * 256 + ds * 32 + hi8);
            Kf[t][ds] = *(const v8s*)(base + (t * 16 + li) * 256 + 64 + ds * 32 + hi8);
        }

    v4f S[4][4];
    #pragma unroll
    for (int qt = 0; qt < 4; qt++)
        #pragma unroll
        for (int kt = 0; kt < 4; kt++) {
            v4f a = (v4f){0.f, 0.f, 0.f, 0.f};
            a = __builtin_amdgcn_mfma_f32_16x16x32_bf16(Qf[qt][0], Kf[kt][0], a, 0, 0, 0);
            a = __builtin_amdgcn_mfma_f32_16x16x32_bf16(Qf[qt][1], Kf[kt][1], a, 0, 0, 0);
            S[qt][kt] = a;
        }

    #pragma unroll
    for (int qt = 0; qt < 4; qt++)
        #pragma unroll
        for (int r = 0; r < 4; r++) {
            float mx = -1e30f;
            #pragma unroll
            for (int kt = 0; kt < 4; kt++) {
                S[qt][kt][r] *= 0.125f;
                mx = fmaxf(mx, S[qt][kt][r]);
            }
            mx = fmaxf(mx, __shfl_xor(mx, 1));
            mx = fmaxf(mx, __shfl_xor(mx, 2));
            mx = fmaxf(mx, __shfl_xor(mx, 4));
            mx = fmaxf(mx, __shfl_xor(mx, 8));
            float sum = 0.f;
            #pragma unroll
            for (int kt = 0; kt < 4; kt++) {
                float e = __expf(S[qt][kt][r] - mx);
                S[qt][kt][r] = e;
                sum += e;
            }
            sum += __shfl_xor(sum, 1);
            sum += __shfl_xor(sum, 2);
            sum += __shfl_xor(sum, 4);
            sum += __shfl_xor(sum, 8);
            float inv = 1.f / sum;
            #pragma unroll
            for (int kt = 0; kt < 4; kt++)
                Ps[(qt * 16 + hi4 + r) * 72 + kt * 16 + li] = f2b(S[qt][kt][r] * inv);
        }

    v4f O[4][4];
    #pragma unroll
    for (int qt = 0; qt < 4; qt++)
        #pragma unroll
        for (int jt = 0; jt < 4; jt++) O[qt][jt] = (v4f){0.f, 0.f, 0.f, 0.f};
    #pragma unroll
    for (int ks = 0; ks < 2; ks++) {
        v8s Pf[4], Vf[4];
        #pragma unroll
        for (int qt = 0; qt < 4; qt++)
            Pf[qt] = *(v8s*)&Ps[(qt * 16 + li) * 72 + ks * 32 + hi8];
        #pragma unroll
        for (int jt = 0; jt < 4; jt++)
            Vf[jt] = *(v8s*)&Vt[(jt * 16 + li) * 72 + ks * 32 + hi8];
        #pragma unroll
        for (int qt = 0; qt < 4; qt++)
            #pragma unroll
            for (int jt = 0; jt < 4; jt++)
                O[qt][jt] = __builtin_amdgcn_mfma_f32_16x16x32_bf16(Pf[qt], Vf[jt], O[qt][jt], 0, 0, 0);
    }

    #pragma unroll
    for (int qt = 0; qt < 4; qt++)
        #pragma unroll
        for (int jt = 0; jt < 4; jt++)
            #pragma unroll
            for (int r = 0; r < 4; r++)
                Ps[(qt * 16 + hi4 + r) * 72 + jt * 16 + li] = f2b(O[qt][jt][r]);
    US* ob = o + (size_t)(g * 64 + l) * 256;
    #pragma unroll
    for (int jv = 0; jv < 8; jv++)
        *(v8us*)(ob + jv * 8) = *(v8us*)&Ps[l * 72 + jv * 8];
}

// ---------------------------------------------------------------- BN affine (stats fused into GEMM epilogue)
__global__ __launch_bounds__(256) void affine_k(const float* __restrict__ g,
                                                const float* __restrict__ b, int sel) {
    int c = threadIdx.x;
    float mean = g_stats[c] / (float)N_NODES;
    float var  = g_stats[CCH + c] / (float)N_NODES - mean * mean;
    float a = g[c] * rsqrtf(var + 1e-5f);
    float* dst = (sel == 0) ? g_aff1 : (sel == 1) ? g_aff2 : g_aff3;
    dst[c] = a;
    dst[CCH + c] = b[c] - mean * a;
    g_stats[c] = 0.f;
    g_stats[CCH + c] = 0.f;
}

// ---------------------------------------------------------------- elementwise (v8us vectorized)
__global__ __launch_bounds__(256) void combine_k(const US* __restrict__ y1,
                                                 const US* __restrict__ y2,
                                                 US* __restrict__ out) {
    size_t idx = (size_t)blockIdx.x * 256 + threadIdx.x;
    size_t stride = (size_t)gridDim.x * 256;
    for (; idx < (size_t)N_NODES * CCH / 8; idx += stride) {
        size_t i = idx * 8;
        int c = (int)(i & 255);
        v8us a = *(const v8us*)(y1 + i);
        v8us b = *(const v8us*)(y2 + i);
        v8us o;
        #pragma unroll
        for (int j = 0; j < 8; j++) {
            float v = b2f(a[j]) * g_aff1[c + j] + g_aff1[CCH + c + j] +
                      b2f(b[j]) * g_aff2[c + j] + g_aff2[CCH + c + j];
            o[j] = f2b(v);
        }
        *(v8us*)(out + i) = o;
    }
}

__global__ __launch_bounds__(256) void apply_k(US* __restrict__ h) {
    size_t idx = (size_t)blockIdx.x * 256 + threadIdx.x;
    size_t stride = (size_t)gridDim.x * 256;
    for (; idx < (size_t)N_NODES * CCH / 8; idx += stride) {
        size_t i = idx * 8;
        int c = (int)(i & 255);
        v8us a = *(const v8us*)(h + i);
        v8us o;
        #pragma unroll
        for (int j = 0; j < 8; j++)
            o[j] = f2b(b2f(a[j]) * g_aff3[c + j] + g_aff3[CCH + c + j]);
        *(v8us*)(h + i) = o;
    }
}

// ---------------------------------------------------------------- pool + head
__global__ __launch_bounds__(256) void pool_k(const US* __restrict__ h,
                                              float* __restrict__ pooled) {
    int g = blockIdx.x, c = threadIdx.x;
    float s = 0.f;
    for (int ss = 0; ss < SEQ; ss++) s += b2f(h[((size_t)g * SEQ + ss) * CCH + c]);
    pooled[(size_t)g * CCH + c] = s;
}

__global__ __launch_bounds__(128) void head_k(const float* __restrict__ pooled,
                                              const float* __restrict__ w1, const float* __restrict__ b1,
                                              const float* __restrict__ w2, const float* __restrict__ b2,
                                              const float* __restrict__ w3, const float* __restrict__ b3,
                                              float* __restrict__ outp) {
    __shared__ float p[256], t1[128], t2[64];
    int g = blockIdx.x, tid = threadIdx.x;
    p[tid] = pooled[(size_t)g * CCH + tid];
    p[tid + 128] = pooled[(size_t)g * CCH + 128 + tid];
    __syncthreads();
    float s = b1[tid];
    for (int k = 0; k < 256; k++) s += p[k] * w1[k * 128 + tid];
    t1[tid] = fmaxf(s, 0.f);
    __syncthreads();
    if (tid < 64) {
        float s2 = b2[tid];
        for (int k = 0; k < 128; k++) s2 += t1[k] * w2[k * 64 + tid];
        t2[tid] = fmaxf(s2, 0.f);
    }
    __syncthreads();
    if (tid == 0) {
        float s3 = b3[0];
        for (int k = 0; k < 64; k++) s3 += t2[k] * w3[k];
        outp[g] = s3;
    }
}

// ================================================================ launch
extern "C" void kernel_launch(void* const* d_in, const int* in_sizes, int n_in,
                              void* d_out, int out_size, void* d_ws, size_t ws_size,
                              hipStream_t stream) {
    const int*   x         = (const int*)  d_in[0];
    const float* pe        = (const float*)d_in[1];
    const int*   ei        = (const int*)  d_in[2];
    const int*   eattr     = (const int*)  d_in[3];
    const float* node_emb  = (const float*)d_in[5];
    const float* pe_lin_w  = (const float*)d_in[6];
    const float* pe_lin_b  = (const float*)d_in[7];
    const float* pe_norm_g = (const float*)d_in[8];
    const float* pe_norm_b = (const float*)d_in[9];
    const float* edge_emb  = (const float*)d_in[10];
    const float* conv_w1   = (const float*)d_in[11];
    const float* conv_b1   = (const float*)d_in[12];
    const float* conv_w2   = (const float*)d_in[13];
    const float* conv_b2   = (const float*)d_in[14];
    const float* attn_in_w = (const float*)d_in[15];
    const float* attn_in_b = (const float*)d_in[16];
    const float* attn_out_w= (const float*)d_in[17];
    const float* attn_out_b= (const float*)d_in[18];
    const float* bn1_g     = (const float*)d_in[19];
    const float* bn1_b     = (const float*)d_in[20];
    const float* bn2_g     = (const float*)d_in[21];
    const float* bn2_b     = (const float*)d_in[22];
    const float* bn3_g     = (const float*)d_in[23];
    const float* bn3_b     = (const float*)d_in[24];
    const float* mlp_w1    = (const float*)d_in[25];
    const float* mlp_b1    = (const float*)d_in[26];
    const float* mlp_w2    = (const float*)d_in[27];
    const float* mlp_b2    = (const float*)d_in[28];
    const float* head_w1   = (const float*)d_in[29];
    const float* head_b1   = (const float*)d_in[30];
    const float* head_w2   = (const float*)d_in[31];
    const float* head_b2   = (const float*)d_in[32];
    const float* head_w3   = (const float*)d_in[33];
    const float* head_b3   = (const float*)d_in[34];
    (void)in_sizes; (void)n_in; (void)out_size; (void)ws_size;

    // workspace: 4 x 64 MB bf16 [N,256] buffers = 256 MB total (proven safe)
    char* ws = (char*)d_ws;
    US* h = (US*)(ws);
    US* A = (US*)(ws + 67108864ULL);
    US* B = (US*)(ws + 134217728ULL);
    US* C = (US*)(ws + 201326592ULL);
    float* pooled = (float*)(ws + 67108864ULL);   // reuses A (dead after layer loop)

    wt_k<<<960, 256, 0, stream>>>(conv_w1, conv_w2, attn_in_w, attn_out_w, mlp_w1, mlp_w2);
    csr_k<<<N_GRAPHS_, 256, 0, stream>>>(ei, eattr);
    pe_part_k<<<256, 256, 0, stream>>>(pe);
    pe_fin_k<<<1, 64, 0, stream>>>(pe_norm_g, pe_norm_b);
    embed_k<<<N_NODES, 256, 0, stream>>>(x, pe, node_emb, pe_lin_w, pe_lin_b, h);

    for (int l = 0; l < LAYERS; l++) {
        size_t wl = (size_t)l * 655360;

        // ---- local GINEConv ----
        aggr_z_k<<<N_GRAPHS_, 256, 0, stream>>>(h, edge_emb, A);                        // z=A
        gemm_mfma_k<4, false><<<1024, 256, 0, stream>>>(A, wl, 256, 0, 64, 128, 192,
                                                        conv_b1 + l * 256, nullptr, B, 1);   // t1
        gemm_mfma_k<4, true><<<1024, 256, 0, stream>>>(B, wl + 65536, 256, 0, 64, 128, 192,
                                                       conv_b2 + l * 256, h, C, 2);          // y1 + stats
        affine_k<<<1, 256, 0, stream>>>(bn1_g + l * 256, bn1_b + l * 256, 0);

        // ---- global attention (per head; q|k|v in A cols 0..191, o in B col blocks) ----
        for (int hh = 0; hh < 4; hh++) {
            gemm_mfma_k<3, false><<<1024, 256, 0, stream>>>(h, wl + 131072, 256,
                                                            hh * 64, 256 + hh * 64, 512 + hh * 64, 0,
                                                            attn_in_b + l * 768, nullptr, A, 0);
            attn_k<<<N_GRAPHS_, 64, 0, stream>>>(A, B + hh * 64);
        }
        gemm_mfma_k<4, true><<<1024, 256, 0, stream>>>(B, wl + 327680, 256, 0, 64, 128, 192,
                                                       attn_out_b + l * 256, h, h, 2);       // y2->h + stats
        affine_k<<<1, 256, 0, stream>>>(bn2_g + l * 256, bn2_b + l * 256, 1);

        // ---- combine + FFN (512-wide hidden in two 256 halves) ----
        combine_k<<<2048, 256, 0, stream>>>(C, h, A);                                        // out=A
        gemm_mfma_k<4, false><<<1024, 256, 0, stream>>>(A, wl + 393216, 256, 0, 64, 128, 192,
                                                        mlp_b1 + l * 512, nullptr, B, 1);    // tA
        gemm_mfma_k<4, false><<<1024, 256, 0, stream>>>(B, wl + 524288, 512, 0, 64, 128, 192,
                                                        mlp_b2 + l * 256, A, C, 2);          // partial
        gemm_mfma_k<4, false><<<1024, 256, 0, stream>>>(A, wl + 393216, 256, 256, 320, 384, 448,
                                                        mlp_b1 + l * 512, nullptr, B, 1);    // tB
        gemm_mfma_k<4, true><<<1024, 256, 0, stream>>>(B, wl + 524288 + 256, 512, 0, 64, 128, 192,
                                                       nullptr, C, h, 2);                    // y3->h + stats
        affine_k<<<1, 256, 0, stream>>>(bn3_g + l * 256, bn3_b + l * 256, 2);
        apply_k<<<2048, 256, 0, stream>>>(h);
    }

    pool_k<<<N_GRAPHS_, 256, 0, stream>>>(h, pooled);
    head_k<<<N_GRAPHS_, 128, 0, stream>>>(pooled, head_w1, head_b1, head_w2, head_b2,
                                          head_w3, head_b3, (float*)d_out);
}

// Round 9
// 5370.443 us; speedup vs baseline: 3.9207x; 1.0694x over previous
//
#include <hip/hip_runtime.h>

#define N_NODES 131072
#define N_EDGES 524288
#define CCH 256
#define N_GRAPHS_ 2048
#define SEQ 64
#define LAYERS 6

typedef unsigned short US;
typedef __attribute__((ext_vector_type(8))) short v8s;           // MFMA bf16 frag
typedef __attribute__((ext_vector_type(8))) unsigned short v8us; // 16B ushort vector
typedef __attribute__((ext_vector_type(4))) float v4f;           // MFMA f32 acc

__device__ __forceinline__ float b2f(US u) { return __uint_as_float(((unsigned)u) << 16); }
__device__ __forceinline__ US f2b(float f) {
    unsigned u = __float_as_uint(f);
    return (US)((u + 0x7fff + ((u >> 16) & 1)) >> 16);   // RNE
}
__device__ __forceinline__ void gload16(const US* g, US* l) {
    __builtin_amdgcn_global_load_lds(
        (const __attribute__((address_space(1))) unsigned int*)g,
        (__attribute__((address_space(3))) unsigned int*)l, 16, 0, 0);
}

// cross-kernel state — referenced ONLY inside device code (never from host!)
__device__ float g_stats[512];
__device__ float g_aff1[512];
__device__ float g_aff2[512];
__device__ float g_aff3[512];
__device__ float g_pe[40];
__device__ float g_peaff[40];
__device__ US    g_wt[6 * 655360];          // per-layer transposed bf16 weights
__device__ int   g_csr[N_EDGES];            // per-graph dst-sorted edges: srcLocal | attr<<6
__device__ int   g_off[N_GRAPHS_ * 65];     // per-graph CSR offsets

// ---------------------------------------------------------------- weight transpose f32[K][C] -> bf16[C][K]
__global__ __launch_bounds__(256) void wt_k(const float* __restrict__ cw1, const float* __restrict__ cw2,
                                            const float* __restrict__ aiw, const float* __restrict__ aow,
                                            const float* __restrict__ mw1, const float* __restrict__ mw2) {
    __shared__ float t[64][65];
    int b = blockIdx.x;
    int l = b / 160, r = b % 160;
    const float* src; int ldw, ldk, ctiles; size_t doff;
    if (r < 16)      { src = cw1 + (size_t)l * 65536;  ldw = 256; ldk = 256; ctiles = 4;  doff = 0;      }
    else if (r < 32) { src = cw2 + (size_t)l * 65536;  ldw = 256; ldk = 256; ctiles = 4;  doff = 65536;  r -= 16; }
    else if (r < 80) { src = aiw + (size_t)l * 196608; ldw = 768; ldk = 256; ctiles = 12; doff = 131072; r -= 32; }
    else if (r < 96) { src = aow + (size_t)l * 65536;  ldw = 256; ldk = 256; ctiles = 4;  doff = 327680; r -= 80; }
    else if (r < 128){ src = mw1 + (size_t)l * 131072; ldw = 512; ldk = 256; ctiles = 8;  doff = 393216; r -= 96; }
    else             { src = mw2 + (size_t)l * 131072; ldw = 256; ldk = 512; ctiles = 4;  doff = 524288; r -= 128; }
    int kt = r / ctiles, ct = r % ctiles;
    int k0 = kt * 64, c0 = ct * 64;
    US* dst = g_wt + (size_t)l * 655360 + doff;
    int tid = threadIdx.x;
    int rr = tid >> 4, c4 = (tid & 15) * 4;
    #pragma unroll
    for (int j = 0; j < 4; j++) {
        float4 v = *(const float4*)(src + (size_t)(k0 + rr + j * 16) * ldw + c0 + c4);
        t[rr + j * 16][c4 + 0] = v.x; t[rr + j * 16][c4 + 1] = v.y;
        t[rr + j * 16][c4 + 2] = v.z; t[rr + j * 16][c4 + 3] = v.w;
    }
    __syncthreads();
    #pragma unroll
    for (int j = 0; j < 4; j++) {
        int crow = rr + j * 16;
        ushort4 o;
        o.x = f2b(t[c4 + 0][crow]); o.y = f2b(t[c4 + 1][crow]);
        o.z = f2b(t[c4 + 2][crow]); o.w = f2b(t[c4 + 3][crow]);
        *(ushort4*)(dst + (size_t)(c0 + crow) * ldk + k0 + c4) = o;
    }
}

// ---------------------------------------------------------------- CSR build (once per launch)
__global__ __launch_bounds__(256) void csr_k(const int* __restrict__ ei,
                                             const int* __restrict__ attr) {
    __shared__ int deg[64], off[65];
    int g = blockIdx.x, tid = threadIdx.x;
    if (tid < 64) deg[tid] = 0;
    __syncthreads();
    int e = g * 256 + tid;
    int d = ei[N_EDGES + e] - g * 64;
    int slot = atomicAdd(&deg[d], 1);
    __syncthreads();
    if (tid == 0) {
        off[0] = 0;
        for (int i = 0; i < 64; i++) off[i + 1] = off[i] + deg[i];
    }
    __syncthreads();
    g_csr[g * 256 + off[d] + slot] = (ei[e] - g * 64) | (attr[e] << 6);
    if (tid < 65) g_off[g * 65 + tid] = off[tid];
}

// ---------------------------------------------------------------- pe stats (2-stage)
__global__ __launch_bounds__(256) void pe_part_k(const float* __restrict__ pe) {
    __shared__ float red[240], red2[240];
    int b = blockIdx.x, tid = threadIdx.x;
    float s = 0.f, s2 = 0.f;
    if (tid < 240) {
        int ch = tid % 20, sub = tid / 20;
        size_t r0 = (size_t)b * 512;
        for (int r = sub; r < 512; r += 12) {
            float v = pe[(r0 + r) * 20 + ch];
            s += v; s2 += v * v;
        }
        red[tid] = s; red2[tid] = s2;
    }
    __syncthreads();
    if (tid < 20) {
        float ts = 0.f, ts2 = 0.f;
        #pragma unroll
        for (int sub = 0; sub < 12; sub++) { ts += red[sub * 20 + tid]; ts2 += red2[sub * 20 + tid]; }
        atomicAdd(&g_pe[tid], ts);
        atomicAdd(&g_pe[20 + tid], ts2);
    }
}

__global__ __launch_bounds__(64) void pe_fin_k(const float* __restrict__ g,
                                               const float* __restrict__ b) {
    int t = threadIdx.x;
    if (t < 20) {
        float mean = g_pe[t] / (float)N_NODES;
        float var  = g_pe[20 + t] / (float)N_NODES - mean * mean;
        float a = g[t] * rsqrtf(var + 1e-5f);
        g_peaff[t] = a;
        g_peaff[20 + t] = b[t] - mean * a;
        g_pe[t] = 0.f;          // re-zero for deterministic replay
        g_pe[20 + t] = 0.f;
    }
}

// ---------------------------------------------------------------- embed
__global__ __launch_bounds__(256) void embed_k(const int* __restrict__ x,
                                               const float* __restrict__ pe,
                                               const float* __restrict__ node_emb,
                                               const float* __restrict__ plw,
                                               const float* __restrict__ plb,
                                               US* __restrict__ h) {
    int n = blockIdx.x;
    int tid = threadIdx.x;
    int xi = x[n];
    float v;
    if (tid < 192) {
        v = node_emb[xi * 192 + tid];
    } else {
        int j = tid - 192;
        float s = plb[j];
        #pragma unroll
        for (int k = 0; k < 20; k++) {
            float p = pe[(size_t)n * 20 + k] * g_peaff[k] + g_peaff[20 + k];
            s += p * plw[k * 64 + j];
        }
        v = s;
    }
    h[(size_t)n * CCH + tid] = f2b(v);
}

// ---------------------------------------------------------------- edge aggregation: CSR, no atomics
__global__ __launch_bounds__(256) void aggr_z_k(const US* __restrict__ h,
                                                const float* __restrict__ eemb,
                                                US* __restrict__ z) {
    __shared__ US ht[64 * 264];
    __shared__ float em[4 * 260];
    __shared__ int off[65], ce[256];
    int g = blockIdx.x, tid = threadIdx.x;
    for (int v = tid; v < 2048; v += 256) {
        int row = v >> 5, seg = (v & 31) * 8;
        *(v8us*)&ht[row * 264 + seg] = *(const v8us*)(h + (size_t)(g * 64 + row) * 256 + seg);
    }
    for (int i = tid; i < 1024; i += 256)
        em[(i >> 8) * 260 + (i & 255)] = eemb[(i >> 8) * 256 + (i & 255)];
    ce[tid] = g_csr[g * 256 + tid];
    if (tid < 65) off[tid] = g_off[g * 65 + tid];
    __syncthreads();

    int dst = tid >> 2, cq = (tid & 3) * 4;
    float acc[64];
    #pragma unroll
    for (int i = 0; i < 64; i++) acc[i] = 0.f;
    int e1 = off[dst + 1];
    for (int e = off[dst]; e < e1; e++) {
        int val = ce[e];
        int src = val & 63, a = (val >> 6) & 3;
        #pragma unroll
        for (int i = 0; i < 16; i++) {
            int c = cq + i * 16;
            ushort4 hv = *(ushort4*)&ht[src * 264 + c];
            float4 ev = *(float4*)&em[a * 260 + c];
            acc[i * 4 + 0] += fmaxf(b2f(hv.x) + ev.x, 0.f);
            acc[i * 4 + 1] += fmaxf(b2f(hv.y) + ev.y, 0.f);
            acc[i * 4 + 2] += fmaxf(b2f(hv.z) + ev.z, 0.f);
            acc[i * 4 + 3] += fmaxf(b2f(hv.w) + ev.w, 0.f);
        }
    }
    US* zp = z + (size_t)(g * 64 + dst) * 256;
    #pragma unroll
    for (int i = 0; i < 16; i++) {
        int c = cq + i * 16;
        ushort4 hv = *(ushort4*)&ht[dst * 264 + c];
        ushort4 o;
        o.x = f2b(b2f(hv.x) + acc[i * 4 + 0]);
        o.y = f2b(b2f(hv.y) + acc[i * 4 + 1]);
        o.z = f2b(b2f(hv.z) + acc[i * 4 + 2]);
        o.w = f2b(b2f(hv.w) + acc[i * 4 + 3]);
        *(ushort4*)(zp + c) = o;
    }
}

// ---------------------------------------------------------------- MFMA bf16 GEMM
// global_load_lds staging, double-buffered LDS, one barrier/chunk, XOR-swizzled layout,
// vectorized transpose epilogue. Block = 128 rows x NG*64 cols (grid 1024).
// mode 0 none, 1 relu, 2 +=res. STATS: column (sum,sumsq) -> g_stats.
template<int NG, bool STATS>
__global__ __launch_bounds__(256, 2) void gemm_mfma_k(const US* __restrict__ A,
                                                      size_t woff, int ldk,
                                                      int w0, int w1, int w2, int w3,
                                                      const float* __restrict__ bias,
                                                      const US* __restrict__ res,
                                                      US* __restrict__ Y, int mode) {
    const US* __restrict__ Wt = g_wt + woff;
    // LDS: As dbuf 2x8KB | Bs dbuf 2x(NG*4KB); epilogue reuses as f32 [32][260]
    __shared__ __align__(16) char smem[16384 + 2 * NG * 4096];
    US* As0 = (US*)smem;
    US* As1 = (US*)(smem + 8192);
    US* Bs0 = (US*)(smem + 16384);
    US* Bs1 = (US*)(smem + 16384 + NG * 4096);
    float* Es = (float*)smem;

    int tid = threadIdx.x;
    size_t row0 = (size_t)blockIdx.x * 128;
    int w = tid >> 6, l = tid & 63;
    int li = l & 15, hi = l >> 4;
    int sl = hi ^ ((li >> 1) & 3);              // frag-read slot swizzle (lane-constant)
    int srow = l >> 2, sslot = l & 3;
    int sko = (sslot ^ ((l >> 3) & 3)) * 8;     // staging source k-offset (inverse swizzle)

    int a_off0 = (w * 32 + li) * 32 + sl * 8;
    int a_off1 = a_off0 + 16 * 32;
    int b_off  = li * 32 + sl * 8;

    v4f acc[2][NG * 4];
    #pragma unroll
    for (int i = 0; i < 2; i++)
        #pragma unroll
        for (int t = 0; t < NG * 4; t++) acc[i][t] = (v4f){0.f, 0.f, 0.f, 0.f};

    auto stage = [&](int kc, US* Asb, US* Bsb) {
        int k0 = kc * 32;
        #pragma unroll
        for (int j = 0; j < 2; j++) {
            int q = w * 2 + j;                      // 16-row group
            gload16(A + (row0 + q * 16 + srow) * 256 + k0 + sko, Asb + q * 512);
        }
        #pragma unroll
        for (int j = 0; j < NG; j++) {
            int q = w * NG + j;                     // 16-col group
            int col = q * 16 + srow;
            int grp = col >> 6;
            int wb = (grp == 0) ? w0 : (grp == 1) ? w1 : (grp == 2) ? w2 : w3;
            gload16(Wt + (size_t)(wb + (col & 63)) * ldk + k0 + sko, Bsb + q * 512);
        }
    };

    stage(0, As0, Bs0);
    __syncthreads();
    for (int kc = 0; kc < 8; kc++) {
        US* Asc = (kc & 1) ? As1 : As0;
        US* Bsc = (kc & 1) ? Bs1 : Bs0;
        if (kc < 7) stage(kc + 1, (kc & 1) ? As0 : As1, (kc & 1) ? Bs0 : Bs1);
        v8s a0 = *(v8s*)(Asc + a_off0);
        v8s a1 = *(v8s*)(Asc + a_off1);
        #pragma unroll
        for (int t = 0; t < NG * 4; t++) {
            v8s bf = *(v8s*)(Bsc + b_off + t * 512);
            acc[0][t] = __builtin_amdgcn_mfma_f32_16x16x32_bf16(a0, bf, acc[0][t], 0, 0, 0);
            acc[1][t] = __builtin_amdgcn_mfma_f32_16x16x32_bf16(a1, bf, acc[1][t], 0, 0, 0);
        }
        __syncthreads();   // drains staged loads; next iter's buffer ready
    }

    // ---- transposed epilogue: 4 passes x 32 rows through Es[32][260] f32 ----
    int er_f = tid >> 3;                 // finish row 0..31
    int lcb = (tid & 7) * 8;             // finish col base
    float csum = 0.f, csum2 = 0.f;
    #pragma unroll
    for (int p = 0; p < 4; p++) {
        int i = p >> 1, wh = p & 1;
        if ((w >> 1) == wh) {            // waves 2wh, 2wh+1 write their acc[i]
            int er0 = (w & 1) * 16 + hi * 4;
            #pragma unroll
            for (int t = 0; t < NG * 4; t++) {
                int grp = t >> 2;
                int wb = (grp == 0) ? w0 : (grp == 1) ? w1 : (grp == 2) ? w2 : w3;
                float bv = bias ? bias[wb + (t & 3) * 16 + li] : 0.f;
                #pragma unroll
                for (int r = 0; r < 4; r++) {
                    float v = acc[i][t][r] + bv;
                    if (mode == 1) v = fmaxf(v, 0.f);
                    Es[(er0 + r) * 260 + t * 16 + li] = v;
                }
            }
        }
        __syncthreads();
        size_t gr = row0 + (size_t)(2 * wh + (er_f >> 4)) * 32 + i * 16 + (er_f & 15);
        #pragma unroll
        for (int s = 0; s < NG; s++) {
            int c = lcb + s * 64;
            float vs[8];
            #pragma unroll
            for (int j = 0; j < 8; j++) vs[j] = Es[er_f * 260 + c + j];
            if (mode == 2) {
                v8us rv = *(const v8us*)(res + gr * 256 + c);
                #pragma unroll
                for (int j = 0; j < 8; j++) vs[j] += b2f(rv[j]);
            }
            v8us yv;
            #pragma unroll
            for (int j = 0; j < 8; j++) yv[j] = f2b(vs[j]);
            *(v8us*)(Y + gr * 256 + c) = yv;
            if constexpr (STATS) {
                #pragma unroll
                for (int j = 0; j < 8; j++) Es[er_f * 260 + c + j] = vs[j];
            }
        }
        if constexpr (STATS) {
            __syncthreads();
            float s1 = 0.f, s2 = 0.f;
            #pragma unroll 8
            for (int r2 = 0; r2 < 32; r2++) {
                float vv = Es[r2 * 260 + tid];
                s1 += vv; s2 += vv * vv;
            }
            csum += s1; csum2 += s2;
        }
        __syncthreads();                 // Es reused next pass
    }
    if constexpr (STATS) {
        atomicAdd(&g_stats[tid], csum);
        atomicAdd(&g_stats[CCH + tid], csum2);
    }
}

// ---------------------------------------------------------------- MFMA attention: 1 wave = (graph, head)
__global__ __launch_bounds__(64) void attn_k(const US* __restrict__ qkv,
                                             US* __restrict__ o) {
    __shared__ __align__(16) US Ps[64 * 72];   // P (then O) tile
    __shared__ __align__(16) US Vt[64 * 72];   // V transposed [d][k]
    int g = blockIdx.x, l = threadIdx.x;
    int li = l & 15, hi8 = (l >> 4) * 8, hi4 = (l >> 4) * 4;
    const US* base = qkv + (size_t)g * 64 * 256;

    {
        v8us vv[8];
        #pragma unroll
        for (int jv = 0; jv < 8; jv++)
            vv[jv] = *(const v8us*)(base + l * 256 + 128 + jv * 8);
        #pragma unroll
        for (int jv = 0; jv < 8; jv++)
            #pragma unroll
            for (int e = 0; e < 8; e++)
                Vt[(jv * 8 + e) * 72 + l] = vv[jv][e];
    }

    v8s Qf[4][2], Kf[4][2];
    #pragma unroll
    for (int t = 0; t < 4; t++)
        #pragma unroll
        for (int ds = 0; ds < 2; ds++) {
            Qf[t][ds] = *(const v8s*)(base + (t * 16 + li) * 256 + ds * 32 + hi8);
            Kf[t][ds] = *(const v8s*)(base + (t * 16 + li) * 256 + 64 + ds * 32 + hi8);
        }

    v4f S[4][4];
    #pragma unroll
    for (int qt = 0; qt < 4; qt++)
        #pragma unroll
        for (int kt = 0; kt < 4; kt++) {
            v4f a = (v4f){0.f, 0.f, 0.f, 0.f};
            a = __builtin_amdgcn_mfma_f32_16x16x32_bf16(Qf[qt][0], Kf[kt][0], a, 0, 0, 0);
            a = __builtin_amdgcn_mfma_f32_16x16x32_bf16(Qf[qt][1], Kf[kt][1], a, 0, 0, 0);
            S[qt][kt] = a;
        }

    #pragma unroll
    for (int qt = 0; qt < 4; qt++)
        #pragma unroll
        for (int r = 0; r < 4; r++) {
            float mx = -1e30f;
            #pragma unroll
            for (int kt = 0; kt < 4; kt++) {
                S[qt][kt][r] *= 0.125f;
                mx = fmaxf(mx, S[qt][kt][r]);
            }
            mx = fmaxf(mx, __shfl_xor(mx, 1));
            mx = fmaxf(mx, __shfl_xor(mx, 2));
            mx = fmaxf(mx, __shfl_xor(mx, 4));
            mx = fmaxf(mx, __shfl_xor(mx, 8));
            float sum = 0.f;
            #pragma unroll
            for (int kt = 0; kt < 4; kt++) {
                float e = __expf(S[qt][kt][r] - mx);
                S[qt][kt][r] = e;
                sum += e;
            }
            sum += __shfl_xor(sum, 1);
            sum += __shfl_xor(sum, 2);
            sum += __shfl_xor(sum, 4);
            sum += __shfl_xor(sum, 8);
            float inv = 1.f / sum;
            #pragma unroll
            for (int kt = 0; kt < 4; kt++)
                Ps[(qt * 16 + hi4 + r) * 72 + kt * 16 + li] = f2b(S[qt][kt][r] * inv);
        }

    v4f O[4][4];
    #pragma unroll
    for (int qt = 0; qt < 4; qt++)
        #pragma unroll
        for (int jt = 0; jt < 4; jt++) O[qt][jt] = (v4f){0.f, 0.f, 0.f, 0.f};
    #pragma unroll
    for (int ks = 0; ks < 2; ks++) {
        v8s Pf[4], Vf[4];
        #pragma unroll
        for (int qt = 0; qt < 4; qt++)
            Pf[qt] = *(v8s*)&Ps[(qt * 16 + li) * 72 + ks * 32 + hi8];
        #pragma unroll
        for (int jt = 0; jt < 4; jt++)
            Vf[jt] = *(v8s*)&Vt[(jt * 16 + li) * 72 + ks * 32 + hi8];
        #pragma unroll
        for (int qt = 0; qt < 4; qt++)
            #pragma unroll
            for (int jt = 0; jt < 4; jt++)
                O[qt][jt] = __builtin_amdgcn_mfma_f32_16x16x32_bf16(Pf[qt], Vf[jt], O[qt][jt], 0, 0, 0);
    }

    #pragma unroll
    for (int qt = 0; qt < 4; qt++)
        #pragma unroll
        for (int jt = 0; jt < 4; jt++)
            #pragma unroll
            for (int r = 0; r < 4; r++)
                Ps[(qt * 16 + hi4 + r) * 72 + jt * 16 + li] = f2b(O[qt][jt][r]);
    US* ob = o + (size_t)(g * 64 + l) * 256;
    #pragma unroll
    for (int jv = 0; jv < 8; jv++)
        *(v8us*)(ob + jv * 8) = *(v8us*)&Ps[l * 72 + jv * 8];
}

// ---------------------------------------------------------------- BN affine (stats fused into GEMM epilogue)
__global__ __launch_bounds__(256) void affine_k(const float* __restrict__ g,
                                                const float* __restrict__ b, int sel) {
    int c = threadIdx.x;
    float mean = g_stats[c] / (float)N_NODES;
    float var  = g_stats[CCH + c] / (float)N_NODES - mean * mean;
    float a = g[c] * rsqrtf(var + 1e-5f);
    float* dst = (sel == 0) ? g_aff1 : (sel == 1) ? g_aff2 : g_aff3;
    dst[c] = a;
    dst[CCH + c] = b[c] - mean * a;
    g_stats[c] = 0.f;
    g_stats[CCH + c] = 0.f;
}

// ---------------------------------------------------------------- elementwise (v8us vectorized)
__global__ __launch_bounds__(256) void combine_k(const US* __restrict__ y1,
                                                 const US* __restrict__ y2,
                                                 US* __restrict__ out) {
    size_t idx = (size_t)blockIdx.x * 256 + threadIdx.x;
    size_t stride = (size_t)gridDim.x * 256;
    for (; idx < (size_t)N_NODES * CCH / 8; idx += stride) {
        size_t i = idx * 8;
        int c = (int)(i & 255);
        v8us a = *(const v8us*)(y1 + i);
        v8us b = *(const v8us*)(y2 + i);
        v8us o;
        #pragma unroll
        for (int j = 0; j < 8; j++) {
            float v = b2f(a[j]) * g_aff1[c + j] + g_aff1[CCH + c + j] +
                      b2f(b[j]) * g_aff2[c + j] + g_aff2[CCH + c + j];
            o[j] = f2b(v);
        }
        *(v8us*)(out + i) = o;
    }
}

__global__ __launch_bounds__(256) void apply_k(US* __restrict__ h) {
    size_t idx = (size_t)blockIdx.x * 256 + threadIdx.x;
    size_t stride = (size_t)gridDim.x * 256;
    for (; idx < (size_t)N_NODES * CCH / 8; idx += stride) {
        size_t i = idx * 8;
        int c = (int)(i & 255);
        v8us a = *(const v8us*)(h + i);
        v8us o;
        #pragma unroll
        for (int j = 0; j < 8; j++)
            o[j] = f2b(b2f(a[j]) * g_aff3[c + j] + g_aff3[CCH + c + j]);
        *(v8us*)(h + i) = o;
    }
}

// ---------------------------------------------------------------- pool + head
__global__ __launch_bounds__(256) void pool_k(const US* __restrict__ h,
                                              float* __restrict__ pooled) {
    int g = blockIdx.x, c = threadIdx.x;
    float s = 0.f;
    for (int ss = 0; ss < SEQ; ss++) s += b2f(h[((size_t)g * SEQ + ss) * CCH + c]);
    pooled[(size_t)g * CCH + c] = s;
}

__global__ __launch_bounds__(128) void head_k(const float* __restrict__ pooled,
                                              const float* __restrict__ w1, const float* __restrict__ b1,
                                              const float* __restrict__ w2, const float* __restrict__ b2,
                                              const float* __restrict__ w3, const float* __restrict__ b3,
                                              float* __restrict__ outp) {
    __shared__ float p[256], t1[128], t2[64];
    int g = blockIdx.x, tid = threadIdx.x;
    p[tid] = pooled[(size_t)g * CCH + tid];
    p[tid + 128] = pooled[(size_t)g * CCH + 128 + tid];
    __syncthreads();
    float s = b1[tid];
    for (int k = 0; k < 256; k++) s += p[k] * w1[k * 128 + tid];
    t1[tid] = fmaxf(s, 0.f);
    __syncthreads();
    if (tid < 64) {
        float s2 = b2[tid];
        for (int k = 0; k < 128; k++) s2 += t1[k] * w2[k * 64 + tid];
        t2[tid] = fmaxf(s2, 0.f);
    }
    __syncthreads();
    if (tid == 0) {
        float s3 = b3[0];
        for (int k = 0; k < 64; k++) s3 += t2[k] * w3[k];
        outp[g] = s3;
    }
}

// ================================================================ launch
extern "C" void kernel_launch(void* const* d_in, const int* in_sizes, int n_in,
                              void* d_out, int out_size, void* d_ws, size_t ws_size,
                              hipStream_t stream) {
    const int*   x         = (const int*)  d_in[0];
    const float* pe        = (const float*)d_in[1];
    const int*   ei        = (const int*)  d_in[2];
    const int*   eattr     = (const int*)  d_in[3];
    const float* node_emb  = (const float*)d_in[5];
    const float* pe_lin_w  = (const float*)d_in[6];
    const float* pe_lin_b  = (const float*)d_in[7];
    const float* pe_norm_g = (const float*)d_in[8];
    const float* pe_norm_b = (const float*)d_in[9];
    const float* edge_emb  = (const float*)d_in[10];
    const float* conv_w1   = (const float*)d_in[11];
    const float* conv_b1   = (const float*)d_in[12];
    const float* conv_w2   = (const float*)d_in[13];
    const float* conv_b2   = (const float*)d_in[14];
    const float* attn_in_w = (const float*)d_in[15];
    const float* attn_in_b = (const float*)d_in[16];
    const float* attn_out_w= (const float*)d_in[17];
    const float* attn_out_b= (const float*)d_in[18];
    const float* bn1_g     = (const float*)d_in[19];
    const float* bn1_b     = (const float*)d_in[20];
    const float* bn2_g     = (const float*)d_in[21];
    const float* bn2_b     = (const float*)d_in[22];
    const float* bn3_g     = (const float*)d_in[23];
    const float* bn3_b     = (const float*)d_in[24];
    const float* mlp_w1    = (const float*)d_in[25];
    const float* mlp_b1    = (const float*)d_in[26];
    const float* mlp_w2    = (const float*)d_in[27];
    const float* mlp_b2    = (const float*)d_in[28];
    const float* head_w1   = (const float*)d_in[29];
    const float* head_b1   = (const float*)d_in[30];
    const float* head_w2   = (const float*)d_in[31];
    const float* head_b2   = (const float*)d_in[32];
    const float* head_w3   = (const float*)d_in[33];
    const float* head_b3   = (const float*)d_in[34];
    (void)in_sizes; (void)n_in; (void)out_size; (void)ws_size;

    // workspace: 4 x 64 MB bf16 [N,256] buffers = 256 MB total (proven safe)
    char* ws = (char*)d_ws;
    US* h = (US*)(ws);
    US* A = (US*)(ws + 67108864ULL);
    US* B = (US*)(ws + 134217728ULL);
    US* C = (US*)(ws + 201326592ULL);
    float* pooled = (float*)(ws + 67108864ULL);   // reuses A (dead after layer loop)

    wt_k<<<960, 256, 0, stream>>>(conv_w1, conv_w2, attn_in_w, attn_out_w, mlp_w1, mlp_w2);
    csr_k<<<N_GRAPHS_, 256, 0, stream>>>(ei, eattr);
    pe_part_k<<<256, 256, 0, stream>>>(pe);
    pe_fin_k<<<1, 64, 0, stream>>>(pe_norm_g, pe_norm_b);
    embed_k<<<N_NODES, 256, 0, stream>>>(x, pe, node_emb, pe_lin_w, pe_lin_b, h);

    for (int l = 0; l < LAYERS; l++) {
        size_t wl = (size_t)l * 655360;

        // ---- local GINEConv ----
        aggr_z_k<<<N_GRAPHS_, 256, 0, stream>>>(h, edge_emb, A);                        // z=A
        gemm_mfma_k<4, false><<<1024, 256, 0, stream>>>(A, wl, 256, 0, 64, 128, 192,
                                                        conv_b1 + l * 256, nullptr, B, 1);   // t1
        gemm_mfma_k<4, true><<<1024, 256, 0, stream>>>(B, wl + 65536, 256, 0, 64, 128, 192,
                                                       conv_b2 + l * 256, h, C, 2);          // y1 + stats
        affine_k<<<1, 256, 0, stream>>>(bn1_g + l * 256, bn1_b + l * 256, 0);

        // ---- global attention (per head; q|k|v in A cols 0..191, o in B col blocks) ----
        for (int hh = 0; hh < 4; hh++) {
            gemm_mfma_k<3, false><<<1024, 256, 0, stream>>>(h, wl + 131072, 256,
                                                            hh * 64, 256 + hh * 64, 512 + hh * 64, 0,
                                                            attn_in_b + l * 768, nullptr, A, 0);
            attn_k<<<N_GRAPHS_, 64, 0, stream>>>(A, B + hh * 64);
        }
        gemm_mfma_k<4, true><<<1024, 256, 0, stream>>>(B, wl + 327680, 256, 0, 64, 128, 192,
                                                       attn_out_b + l * 256, h, h, 2);       // y2->h + stats
        affine_k<<<1, 256, 0, stream>>>(bn2_g + l * 256, bn2_b + l * 256, 1);

        // ---- combine + FFN (512-wide hidden in two 256 halves) ----
        combine_k<<<2048, 256, 0, stream>>>(C, h, A);                                        // out=A
        gemm_mfma_k<4, false><<<1024, 256, 0, stream>>>(A, wl + 393216, 256, 0, 64, 128, 192,
                                                        mlp_b1 + l * 512, nullptr, B, 1);    // tA
        gemm_mfma_k<4, false><<<1024, 256, 0, stream>>>(B, wl + 524288, 512, 0, 64, 128, 192,
                                                        mlp_b2 + l * 256, A, C, 2);          // partial
        gemm_mfma_k<4, false><<<1024, 256, 0, stream>>>(A, wl + 393216, 256, 256, 320, 384, 448,
                                                        mlp_b1 + l * 512, nullptr, B, 1);    // tB
        gemm_mfma_k<4, true><<<1024, 256, 0, stream>>>(B, wl + 524288 + 256, 512, 0, 64, 128, 192,
                                                       nullptr, C, h, 2);                    // y3->h + stats
        affine_k<<<1, 256, 0, stream>>>(bn3_g + l * 256, bn3_b + l * 256, 2);
        apply_k<<<2048, 256, 0, stream>>>(h);
    }

    pool_k<<<N_GRAPHS_, 256, 0, stream>>>(h, pooled);
    head_k<<<N_GRAPHS_, 128, 0, stream>>>(pooled, head_w1, head_b1, head_w2, head_b2,
                                          head_w3, head_b3, (float*)d_out);
}

// Round 10
// 5165.292 us; speedup vs baseline: 4.0765x; 1.0397x over previous
//
#include <hip/hip_runtime.h>

#define N_NODES 131072
#define N_EDGES 524288
#define CCH 256
#define N_GRAPHS_ 2048
#define SEQ 64
#define LAYERS 6

typedef unsigned short US;
typedef __attribute__((ext_vector_type(8))) short v8s;           // MFMA bf16 frag
typedef __attribute__((ext_vector_type(8))) unsigned short v8us; // 16B ushort vector
typedef __attribute__((ext_vector_type(4))) float v4f;           // MFMA f32 acc

__device__ __forceinline__ float b2f(US u) { return __uint_as_float(((unsigned)u) << 16); }
__device__ __forceinline__ US f2b(float f) {
    unsigned u = __float_as_uint(f);
    return (US)((u + 0x7fff + ((u >> 16) & 1)) >> 16);   // RNE
}
__device__ __forceinline__ void gload16(const US* g, US* l) {
    __builtin_amdgcn_global_load_lds(
        (const __attribute__((address_space(1))) unsigned int*)g,
        (__attribute__((address_space(3))) unsigned int*)l, 16, 0, 0);
}

// cross-kernel state — referenced ONLY inside device code (never from host!)
__device__ float g_stats[512];
__device__ float g_aff1[512];
__device__ float g_aff2[512];
__device__ float g_aff3[512];
__device__ float g_pe[40];
__device__ float g_peaff[40];
__device__ US    g_wt[6 * 655360];          // per-layer transposed bf16 weights
__device__ int   g_csr[N_EDGES];            // per-graph dst-sorted edges: srcLocal | attr<<6
__device__ int   g_off[N_GRAPHS_ * 65];     // per-graph CSR offsets

// ---------------------------------------------------------------- weight transpose f32[K][C] -> bf16[C][K]
__global__ __launch_bounds__(256) void wt_k(const float* __restrict__ cw1, const float* __restrict__ cw2,
                                            const float* __restrict__ aiw, const float* __restrict__ aow,
                                            const float* __restrict__ mw1, const float* __restrict__ mw2) {
    __shared__ float t[64][65];
    int b = blockIdx.x;
    int l = b / 160, r = b % 160;
    const float* src; int ldw, ldk, ctiles; size_t doff;
    if (r < 16)      { src = cw1 + (size_t)l * 65536;  ldw = 256; ldk = 256; ctiles = 4;  doff = 0;      }
    else if (r < 32) { src = cw2 + (size_t)l * 65536;  ldw = 256; ldk = 256; ctiles = 4;  doff = 65536;  r -= 16; }
    else if (r < 80) { src = aiw + (size_t)l * 196608; ldw = 768; ldk = 256; ctiles = 12; doff = 131072; r -= 32; }
    else if (r < 96) { src = aow + (size_t)l * 65536;  ldw = 256; ldk = 256; ctiles = 4;  doff = 327680; r -= 80; }
    else if (r < 128){ src = mw1 + (size_t)l * 131072; ldw = 512; ldk = 256; ctiles = 8;  doff = 393216; r -= 96; }
    else             { src = mw2 + (size_t)l * 131072; ldw = 256; ldk = 512; ctiles = 4;  doff = 524288; r -= 128; }
    int kt = r / ctiles, ct = r % ctiles;
    int k0 = kt * 64, c0 = ct * 64;
    US* dst = g_wt + (size_t)l * 655360 + doff;
    int tid = threadIdx.x;
    int rr = tid >> 4, c4 = (tid & 15) * 4;
    #pragma unroll
    for (int j = 0; j < 4; j++) {
        float4 v = *(const float4*)(src + (size_t)(k0 + rr + j * 16) * ldw + c0 + c4);
        t[rr + j * 16][c4 + 0] = v.x; t[rr + j * 16][c4 + 1] = v.y;
        t[rr + j * 16][c4 + 2] = v.z; t[rr + j * 16][c4 + 3] = v.w;
    }
    __syncthreads();
    #pragma unroll
    for (int j = 0; j < 4; j++) {
        int crow = rr + j * 16;
        ushort4 o;
        o.x = f2b(t[c4 + 0][crow]); o.y = f2b(t[c4 + 1][crow]);
        o.z = f2b(t[c4 + 2][crow]); o.w = f2b(t[c4 + 3][crow]);
        *(ushort4*)(dst + (size_t)(c0 + crow) * ldk + k0 + c4) = o;
    }
}

// ---------------------------------------------------------------- CSR build (once per launch)
__global__ __launch_bounds__(256) void csr_k(const int* __restrict__ ei,
                                             const int* __restrict__ attr) {
    __shared__ int deg[64], off[65];
    int g = blockIdx.x, tid = threadIdx.x;
    if (tid < 64) deg[tid] = 0;
    __syncthreads();
    int e = g * 256 + tid;
    int d = ei[N_EDGES + e] - g * 64;
    int slot = atomicAdd(&deg[d], 1);
    __syncthreads();
    if (tid == 0) {
        off[0] = 0;
        for (int i = 0; i < 64; i++) off[i + 1] = off[i] + deg[i];
    }
    __syncthreads();
    g_csr[g * 256 + off[d] + slot] = (ei[e] - g * 64) | (attr[e] << 6);
    if (tid < 65) g_off[g * 65 + tid] = off[tid];
}

// ---------------------------------------------------------------- pe stats (2-stage)
__global__ __launch_bounds__(256) void pe_part_k(const float* __restrict__ pe) {
    __shared__ float red[240], red2[240];
    int b = blockIdx.x, tid = threadIdx.x;
    float s = 0.f, s2 = 0.f;
    if (tid < 240) {
        int ch = tid % 20, sub = tid / 20;
        size_t r0 = (size_t)b * 512;
        for (int r = sub; r < 512; r += 12) {
            float v = pe[(r0 + r) * 20 + ch];
            s += v; s2 += v * v;
        }
        red[tid] = s; red2[tid] = s2;
    }
    __syncthreads();
    if (tid < 20) {
        float ts = 0.f, ts2 = 0.f;
        #pragma unroll
        for (int sub = 0; sub < 12; sub++) { ts += red[sub * 20 + tid]; ts2 += red2[sub * 20 + tid]; }
        atomicAdd(&g_pe[tid], ts);
        atomicAdd(&g_pe[20 + tid], ts2);
    }
}

__global__ __launch_bounds__(64) void pe_fin_k(const float* __restrict__ g,
                                               const float* __restrict__ b) {
    int t = threadIdx.x;
    if (t < 20) {
        float mean = g_pe[t] / (float)N_NODES;
        float var  = g_pe[20 + t] / (float)N_NODES - mean * mean;
        float a = g[t] * rsqrtf(var + 1e-5f);
        g_peaff[t] = a;
        g_peaff[20 + t] = b[t] - mean * a;
        g_pe[t] = 0.f;          // re-zero for deterministic replay
        g_pe[20 + t] = 0.f;
    }
}

// ---------------------------------------------------------------- embed
__global__ __launch_bounds__(256) void embed_k(const int* __restrict__ x,
                                               const float* __restrict__ pe,
                                               const float* __restrict__ node_emb,
                                               const float* __restrict__ plw,
                                               const float* __restrict__ plb,
                                               US* __restrict__ h) {
    int n = blockIdx.x;
    int tid = threadIdx.x;
    int xi = x[n];
    float v;
    if (tid < 192) {
        v = node_emb[xi * 192 + tid];
    } else {
        int j = tid - 192;
        float s = plb[j];
        #pragma unroll
        for (int k = 0; k < 20; k++) {
            float p = pe[(size_t)n * 20 + k] * g_peaff[k] + g_peaff[20 + k];
            s += p * plw[k * 64 + j];
        }
        v = s;
    }
    h[(size_t)n * CCH + tid] = f2b(v);
}

// ---------------------------------------------------------------- edge aggregation: CSR, no atomics
__global__ __launch_bounds__(256) void aggr_z_k(const US* __restrict__ h,
                                                const float* __restrict__ eemb,
                                                US* __restrict__ z) {
    __shared__ US ht[64 * 264];
    __shared__ float em[4 * 260];
    __shared__ int off[65], ce[256];
    int g = blockIdx.x, tid = threadIdx.x;
    for (int v = tid; v < 2048; v += 256) {
        int row = v >> 5, seg = (v & 31) * 8;
        *(v8us*)&ht[row * 264 + seg] = *(const v8us*)(h + (size_t)(g * 64 + row) * 256 + seg);
    }
    for (int i = tid; i < 1024; i += 256)
        em[(i >> 8) * 260 + (i & 255)] = eemb[(i >> 8) * 256 + (i & 255)];
    ce[tid] = g_csr[g * 256 + tid];
    if (tid < 65) off[tid] = g_off[g * 65 + tid];
    __syncthreads();

    int dst = tid >> 2, cq = (tid & 3) * 4;
    float acc[64];
    #pragma unroll
    for (int i = 0; i < 64; i++) acc[i] = 0.f;
    int e1 = off[dst + 1];
    for (int e = off[dst]; e < e1; e++) {
        int val = ce[e];
        int src = val & 63, a = (val >> 6) & 3;
        #pragma unroll
        for (int i = 0; i < 16; i++) {
            int c = cq + i * 16;
            ushort4 hv = *(ushort4*)&ht[src * 264 + c];
            float4 ev = *(float4*)&em[a * 260 + c];
            acc[i * 4 + 0] += fmaxf(b2f(hv.x) + ev.x, 0.f);
            acc[i * 4 + 1] += fmaxf(b2f(hv.y) + ev.y, 0.f);
            acc[i * 4 + 2] += fmaxf(b2f(hv.z) + ev.z, 0.f);
            acc[i * 4 + 3] += fmaxf(b2f(hv.w) + ev.w, 0.f);
        }
    }
    US* zp = z + (size_t)(g * 64 + dst) * 256;
    #pragma unroll
    for (int i = 0; i < 16; i++) {
        int c = cq + i * 16;
        ushort4 hv = *(ushort4*)&ht[dst * 264 + c];
        ushort4 o;
        o.x = f2b(b2f(hv.x) + acc[i * 4 + 0]);
        o.y = f2b(b2f(hv.y) + acc[i * 4 + 1]);
        o.z = f2b(b2f(hv.z) + acc[i * 4 + 2]);
        o.w = f2b(b2f(hv.w) + acc[i * 4 + 3]);
        *(ushort4*)(zp + c) = o;
    }
}

// ---------------------------------------------------------------- MFMA bf16 GEMM  (BM=64, high occupancy)
// Block = 64 rows x NG*64 cols, grid 2048 (XCD-swizzled). Wave w owns rows w*16..w*16+15.
// global_load_lds staging, double-buffered LDS, XOR-swizzled slots, transposed epilogue.
// mode 0 none, 1 relu, 2 +=res. STATS: column (sum,sumsq) -> g_stats.
template<int NG, bool STATS>
__global__ __launch_bounds__(256, 4) void gemm_mfma_k(const US* __restrict__ A,
                                                      size_t woff, int ldk,
                                                      int w0, int w1, int w2, int w3,
                                                      const float* __restrict__ bias,
                                                      const US* __restrict__ res,
                                                      US* __restrict__ Y, int mode) {
    const US* __restrict__ Wt = g_wt + woff;
    // LDS: As dbuf 2x4KB | Bs dbuf 2x(NG*4KB); epilogue reuses as f32 [32][NG*64+4]
    __shared__ __align__(16) char smem[8192 + 2 * NG * 4096];
    US* As0 = (US*)smem;
    US* As1 = As0 + 2048;
    US* Bs0 = (US*)(smem + 8192);
    US* Bs1 = Bs0 + NG * 2048;
    float* Es = (float*)smem;
    const int NW = NG * 64 + 4;

    int tid = threadIdx.x;
    int bid = blockIdx.x;
    int swz = (bid & 7) * ((int)gridDim.x >> 3) + (bid >> 3);   // XCD-aware, bijective (2048%8==0)
    size_t row0 = (size_t)swz * 64;
    int w = tid >> 6, l = tid & 63;
    int li = l & 15, hi = l >> 4;
    int sl = hi ^ ((li >> 1) & 3);              // frag-read slot swizzle
    int sr = l >> 2, ss = l & 3;                // staging: row-in-16, slot

    int a_off = (w * 16 + li) * 32 + sl * 8;

    v4f acc[NG * 4];
    #pragma unroll
    for (int t = 0; t < NG * 4; t++) acc[t] = (v4f){0.f, 0.f, 0.f, 0.f};

    // staging source addresses (k0-invariant parts)
    int ar = w * 16 + sr;                                  // A row this lane stages
    int akg = (ss ^ ((ar >> 1) & 3)) * 8;                  // inverse-swizzled k-offset
    const US* asrc = A + (row0 + ar) * 256 + akg;

    auto stage = [&](int kc, US* Asb, US* Bsb) {
        int k0 = kc * 32;
        gload16(asrc + k0, Asb + w * 512);                 // wave-uniform dest base
        #pragma unroll
        for (int j = 0; j < NG; j++) {
            int cu = (j * 4 + w) * 16 + sr;                // col 0..NG*64-1
            int grp = cu >> 6;
            int wb = (grp == 0) ? w0 : (grp == 1) ? w1 : (grp == 2) ? w2 : w3;
            int kg = (ss ^ ((cu >> 1) & 3)) * 8;
            gload16(Wt + (size_t)(wb + (cu & 63)) * ldk + k0 + kg,
                    Bsb + (j * 4 + w) * 512);
        }
    };

    stage(0, As0, Bs0);
    __syncthreads();
    for (int kc = 0; kc < 8; kc++) {
        US* Asc = (kc & 1) ? As1 : As0;
        US* Bsc = (kc & 1) ? Bs1 : Bs0;
        if (kc < 7) stage(kc + 1, (kc & 1) ? As0 : As1, (kc & 1) ? Bs0 : Bs1);
        v8s a0 = *(v8s*)(Asc + a_off);
        #pragma unroll
        for (int t = 0; t < NG * 4; t++) {
            v8s bf = *(v8s*)(Bsc + (t * 16 + li) * 32 + sl * 8);
            acc[t] = __builtin_amdgcn_mfma_f32_16x16x32_bf16(a0, bf, acc[t], 0, 0, 0);
        }
        __syncthreads();   // drains staged loads; next iter's buffer ready
    }

    // ---- transposed epilogue: 2 passes x 32 rows through Es[32][NW] f32 ----
    int er_f = tid >> 3;                 // finish row 0..31
    int lcb = (tid & 7) * 8;             // finish col base within 64-group
    float csum = 0.f, csum2 = 0.f;
    #pragma unroll
    for (int p = 0; p < 2; p++) {
        if ((w >> 1) == p) {             // waves 2p, 2p+1 write their acc
            int er0 = (w & 1) * 16 + hi * 4;
            #pragma unroll
            for (int t = 0; t < NG * 4; t++) {
                int grp = t >> 2;
                int wb = (grp == 0) ? w0 : (grp == 1) ? w1 : (grp == 2) ? w2 : w3;
                float bv = bias ? bias[wb + (t & 3) * 16 + li] : 0.f;
                #pragma unroll
                for (int r = 0; r < 4; r++) {
                    float v = acc[t][r] + bv;
                    if (mode == 1) v = fmaxf(v, 0.f);
                    Es[(er0 + r) * NW + t * 16 + li] = v;
                }
            }
        }
        __syncthreads();
        size_t gr = row0 + p * 32 + er_f;
        #pragma unroll
        for (int s = 0; s < NG; s++) {
            int c = s * 64 + lcb;
            float vs[8];
            #pragma unroll
            for (int j = 0; j < 8; j++) vs[j] = Es[er_f * NW + c + j];
            if (mode == 2) {
                v8us rv = *(const v8us*)(res + gr * 256 + c);
                #pragma unroll
                for (int j = 0; j < 8; j++) vs[j] += b2f(rv[j]);
            }
            v8us yv;
            #pragma unroll
            for (int j = 0; j < 8; j++) yv[j] = f2b(vs[j]);
            *(v8us*)(Y + gr * 256 + c) = yv;
            if constexpr (STATS) {
                #pragma unroll
                for (int j = 0; j < 8; j++) Es[er_f * NW + c + j] = vs[j];
            }
        }
        if constexpr (STATS) {
            __syncthreads();
            if (tid < NG * 64) {
                float s1 = 0.f, s2 = 0.f;
                #pragma unroll 8
                for (int r2 = 0; r2 < 32; r2++) {
                    float vv = Es[r2 * NW + tid];
                    s1 += vv; s2 += vv * vv;
                }
                csum += s1; csum2 += s2;
            }
        }
        __syncthreads();                 // Es reused next pass
    }
    if constexpr (STATS) {
        if (tid < NG * 64) {
            atomicAdd(&g_stats[tid], csum);
            atomicAdd(&g_stats[CCH + tid], csum2);
        }
    }
}

// ---------------------------------------------------------------- MFMA attention: 1 wave = (graph, head)
__global__ __launch_bounds__(64) void attn_k(const US* __restrict__ qkv,
                                             US* __restrict__ o) {
    __shared__ __align__(16) US Ps[64 * 72];   // P (then O) tile
    __shared__ __align__(16) US Vt[64 * 72];   // V transposed [d][k]
    int g = blockIdx.x, l = threadIdx.x;
    int li = l & 15, hi8 = (l >> 4) * 8, hi4 = (l >> 4) * 4;
    const US* base = qkv + (size_t)g * 64 * 256;

    {
        v8us vv[8];
        #pragma unroll
        for (int jv = 0; jv < 8; jv++)
            vv[jv] = *(const v8us*)(base + l * 256 + 128 + jv * 8);
        #pragma unroll
        for (int jv = 0; jv < 8; jv++)
            #pragma unroll
            for (int e = 0; e < 8; e++)
                Vt[(jv * 8 + e) * 72 + l] = vv[jv][e];
    }

    v8s Qf[4][2], Kf[4][2];
    #pragma unroll
    for (int t = 0; t < 4; t++)
        #pragma unroll
        for (int ds = 0; ds < 2; ds++) {
            Qf[t][ds] = *(const v8s*)(base + (t * 16 + li) * 256 + ds * 32 + hi8);
            Kf[t][ds] = *(const v8s*)(base + (t * 16 + li) * 256 + 64 + ds * 32 + hi8);
        }

    v4f S[4][4];
    #pragma unroll
    for (int qt = 0; qt < 4; qt++)
        #pragma unroll
        for (int kt = 0; kt < 4; kt++) {
            v4f a = (v4f){0.f, 0.f, 0.f, 0.f};
            a = __builtin_amdgcn_mfma_f32_16x16x32_bf16(Qf[qt][0], Kf[kt][0], a, 0, 0, 0);
            a = __builtin_amdgcn_mfma_f32_16x16x32_bf16(Qf[qt][1], Kf[kt][1], a, 0, 0, 0);
            S[qt][kt] = a;
        }

    #pragma unroll
    for (int qt = 0; qt < 4; qt++)
        #pragma unroll
        for (int r = 0; r < 4; r++) {
            float mx = -1e30f;
            #pragma unroll
            for (int kt = 0; kt < 4; kt++) {
                S[qt][kt][r] *= 0.125f;
                mx = fmaxf(mx, S[qt][kt][r]);
            }
            mx = fmaxf(mx, __shfl_xor(mx, 1));
            mx = fmaxf(mx, __shfl_xor(mx, 2));
            mx = fmaxf(mx, __shfl_xor(mx, 4));
            mx = fmaxf(mx, __shfl_xor(mx, 8));
            float sum = 0.f;
            #pragma unroll
            for (int kt = 0; kt < 4; kt++) {
                float e = __expf(S[qt][kt][r] - mx);
                S[qt][kt][r] = e;
                sum += e;
            }
            sum += __shfl_xor(sum, 1);
            sum += __shfl_xor(sum, 2);
            sum += __shfl_xor(sum, 4);
            sum += __shfl_xor(sum, 8);
            float inv = 1.f / sum;
            #pragma unroll
            for (int kt = 0; kt < 4; kt++)
                Ps[(qt * 16 + hi4 + r) * 72 + kt * 16 + li] = f2b(S[qt][kt][r] * inv);
        }

    v4f O[4][4];
    #pragma unroll
    for (int qt = 0; qt < 4; qt++)
        #pragma unroll
        for (int jt = 0; jt < 4; jt++) O[qt][jt] = (v4f){0.f, 0.f, 0.f, 0.f};
    #pragma unroll
    for (int ks = 0; ks < 2; ks++) {
        v8s Pf[4], Vf[4];
        #pragma unroll
        for (int qt = 0; qt < 4; qt++)
            Pf[qt] = *(v8s*)&Ps[(qt * 16 + li) * 72 + ks * 32 + hi8];
        #pragma unroll
        for (int jt = 0; jt < 4; jt++)
            Vf[jt] = *(v8s*)&Vt[(jt * 16 + li) * 72 + ks * 32 + hi8];
        #pragma unroll
        for (int qt = 0; qt < 4; qt++)
            #pragma unroll
            for (int jt = 0; jt < 4; jt++)
                O[qt][jt] = __builtin_amdgcn_mfma_f32_16x16x32_bf16(Pf[qt], Vf[jt], O[qt][jt], 0, 0, 0);
    }

    #pragma unroll
    for (int qt = 0; qt < 4; qt++)
        #pragma unroll
        for (int jt = 0; jt < 4; jt++)
            #pragma unroll
            for (int r = 0; r < 4; r++)
                Ps[(qt * 16 + hi4 + r) * 72 + jt * 16 + li] = f2b(O[qt][jt][r]);
    US* ob = o + (size_t)(g * 64 + l) * 256;
    #pragma unroll
    for (int jv = 0; jv < 8; jv++)
        *(v8us*)(ob + jv * 8) = *(v8us*)&Ps[l * 72 + jv * 8];
}

// ---------------------------------------------------------------- BN affine (stats fused into GEMM epilogue)
__global__ __launch_bounds__(256) void affine_k(const float* __restrict__ g,
                                                const float* __restrict__ b, int sel) {
    int c = threadIdx.x;
    float mean = g_stats[c] / (float)N_NODES;
    float var  = g_stats[CCH + c] / (float)N_NODES - mean * mean;
    float a = g[c] * rsqrtf(var + 1e-5f);
    float* dst = (sel == 0) ? g_aff1 : (sel == 1) ? g_aff2 : g_aff3;
    dst[c] = a;
    dst[CCH + c] = b[c] - mean * a;
    g_stats[c] = 0.f;
    g_stats[CCH + c] = 0.f;
}

// ---------------------------------------------------------------- elementwise (v8us vectorized)
__global__ __launch_bounds__(256) void combine_k(const US* __restrict__ y1,
                                                 const US* __restrict__ y2,
                                                 US* __restrict__ out) {
    size_t idx = (size_t)blockIdx.x * 256 + threadIdx.x;
    size_t stride = (size_t)gridDim.x * 256;
    for (; idx < (size_t)N_NODES * CCH / 8; idx += stride) {
        size_t i = idx * 8;
        int c = (int)(i & 255);
        v8us a = *(const v8us*)(y1 + i);
        v8us b = *(const v8us*)(y2 + i);
        v8us o;
        #pragma unroll
        for (int j = 0; j < 8; j++) {
            float v = b2f(a[j]) * g_aff1[c + j] + g_aff1[CCH + c + j] +
                      b2f(b[j]) * g_aff2[c + j] + g_aff2[CCH + c + j];
            o[j] = f2b(v);
        }
        *(v8us*)(out + i) = o;
    }
}

__global__ __launch_bounds__(256) void apply_k(US* __restrict__ h) {
    size_t idx = (size_t)blockIdx.x * 256 + threadIdx.x;
    size_t stride = (size_t)gridDim.x * 256;
    for (; idx < (size_t)N_NODES * CCH / 8; idx += stride) {
        size_t i = idx * 8;
        int c = (int)(i & 255);
        v8us a = *(const v8us*)(h + i);
        v8us o;
        #pragma unroll
        for (int j = 0; j < 8; j++)
            o[j] = f2b(b2f(a[j]) * g_aff3[c + j] + g_aff3[CCH + c + j]);
        *(v8us*)(h + i) = o;
    }
}

// ---------------------------------------------------------------- pool + head
__global__ __launch_bounds__(256) void pool_k(const US* __restrict__ h,
                                              float* __restrict__ pooled) {
    int g = blockIdx.x, c = threadIdx.x;
    float s = 0.f;
    for (int ss = 0; ss < SEQ; ss++) s += b2f(h[((size_t)g * SEQ + ss) * CCH + c]);
    pooled[(size_t)g * CCH + c] = s;
}

__global__ __launch_bounds__(128) void head_k(const float* __restrict__ pooled,
                                              const float* __restrict__ w1, const float* __restrict__ b1,
                                              const float* __restrict__ w2, const float* __restrict__ b2,
                                              const float* __restrict__ w3, const float* __restrict__ b3,
                                              float* __restrict__ outp) {
    __shared__ float p[256], t1[128], t2[64];
    int g = blockIdx.x, tid = threadIdx.x;
    p[tid] = pooled[(size_t)g * CCH + tid];
    p[tid + 128] = pooled[(size_t)g * CCH + 128 + tid];
    __syncthreads();
    float s = b1[tid];
    for (int k = 0; k < 256; k++) s += p[k] * w1[k * 128 + tid];
    t1[tid] = fmaxf(s, 0.f);
    __syncthreads();
    if (tid < 64) {
        float s2 = b2[tid];
        for (int k = 0; k < 128; k++) s2 += t1[k] * w2[k * 64 + tid];
        t2[tid] = fmaxf(s2, 0.f);
    }
    __syncthreads();
    if (tid == 0) {
        float s3 = b3[0];
        for (int k = 0; k < 64; k++) s3 += t2[k] * w3[k];
        outp[g] = s3;
    }
}

// ================================================================ launch
extern "C" void kernel_launch(void* const* d_in, const int* in_sizes, int n_in,
                              void* d_out, int out_size, void* d_ws, size_t ws_size,
                              hipStream_t stream) {
    const int*   x         = (const int*)  d_in[0];
    const float* pe        = (const float*)d_in[1];
    const int*   ei        = (const int*)  d_in[2];
    const int*   eattr     = (const int*)  d_in[3];
    const float* node_emb  = (const float*)d_in[5];
    const float* pe_lin_w  = (const float*)d_in[6];
    const float* pe_lin_b  = (const float*)d_in[7];
    const float* pe_norm_g = (const float*)d_in[8];
    const float* pe_norm_b = (const float*)d_in[9];
    const float* edge_emb  = (const float*)d_in[10];
    const float* conv_w1   = (const float*)d_in[11];
    const float* conv_b1   = (const float*)d_in[12];
    const float* conv_w2   = (const float*)d_in[13];
    const float* conv_b2   = (const float*)d_in[14];
    const float* attn_in_w = (const float*)d_in[15];
    const float* attn_in_b = (const float*)d_in[16];
    const float* attn_out_w= (const float*)d_in[17];
    const float* attn_out_b= (const float*)d_in[18];
    const float* bn1_g     = (const float*)d_in[19];
    const float* bn1_b     = (const float*)d_in[20];
    const float* bn2_g     = (const float*)d_in[21];
    const float* bn2_b     = (const float*)d_in[22];
    const float* bn3_g     = (const float*)d_in[23];
    const float* bn3_b     = (const float*)d_in[24];
    const float* mlp_w1    = (const float*)d_in[25];
    const float* mlp_b1    = (const float*)d_in[26];
    const float* mlp_w2    = (const float*)d_in[27];
    const float* mlp_b2    = (const float*)d_in[28];
    const float* head_w1   = (const float*)d_in[29];
    const float* head_b1   = (const float*)d_in[30];
    const float* head_w2   = (const float*)d_in[31];
    const float* head_b2   = (const float*)d_in[32];
    const float* head_w3   = (const float*)d_in[33];
    const float* head_b3   = (const float*)d_in[34];
    (void)in_sizes; (void)n_in; (void)out_size; (void)ws_size;

    // workspace: 4 x 64 MB bf16 [N,256] buffers = 256 MB total (proven safe)
    char* ws = (char*)d_ws;
    US* h = (US*)(ws);
    US* A = (US*)(ws + 67108864ULL);
    US* B = (US*)(ws + 134217728ULL);
    US* C = (US*)(ws + 201326592ULL);
    float* pooled = (float*)(ws + 67108864ULL);   // reuses A (dead after layer loop)

    wt_k<<<960, 256, 0, stream>>>(conv_w1, conv_w2, attn_in_w, attn_out_w, mlp_w1, mlp_w2);
    csr_k<<<N_GRAPHS_, 256, 0, stream>>>(ei, eattr);
    pe_part_k<<<256, 256, 0, stream>>>(pe);
    pe_fin_k<<<1, 64, 0, stream>>>(pe_norm_g, pe_norm_b);
    embed_k<<<N_NODES, 256, 0, stream>>>(x, pe, node_emb, pe_lin_w, pe_lin_b, h);

    for (int l = 0; l < LAYERS; l++) {
        size_t wl = (size_t)l * 655360;

        // ---- local GINEConv ----
        aggr_z_k<<<N_GRAPHS_, 256, 0, stream>>>(h, edge_emb, A);                        // z=A
        gemm_mfma_k<4, false><<<2048, 256, 0, stream>>>(A, wl, 256, 0, 64, 128, 192,
                                                        conv_b1 + l * 256, nullptr, B, 1);   // t1
        gemm_mfma_k<4, true><<<2048, 256, 0, stream>>>(B, wl + 65536, 256, 0, 64, 128, 192,
                                                       conv_b2 + l * 256, h, C, 2);          // y1 + stats
        affine_k<<<1, 256, 0, stream>>>(bn1_g + l * 256, bn1_b + l * 256, 0);

        // ---- global attention (per head; q|k|v in A cols 0..191, o in B col blocks) ----
        for (int hh = 0; hh < 4; hh++) {
            gemm_mfma_k<3, false><<<2048, 256, 0, stream>>>(h, wl + 131072, 256,
                                                            hh * 64, 256 + hh * 64, 512 + hh * 64, 0,
                                                            attn_in_b + l * 768, nullptr, A, 0);
            attn_k<<<N_GRAPHS_, 64, 0, stream>>>(A, B + hh * 64);
        }
        gemm_mfma_k<4, true><<<2048, 256, 0, stream>>>(B, wl + 327680, 256, 0, 64, 128, 192,
                                                       attn_out_b + l * 256, h, h, 2);       // y2->h + stats
        affine_k<<<1, 256, 0, stream>>>(bn2_g + l * 256, bn2_b + l * 256, 1);

        // ---- combine + FFN (512-wide hidden in two 256 halves) ----
        combine_k<<<2048, 256, 0, stream>>>(C, h, A);                                        // out=A
        gemm_mfma_k<4, false><<<2048, 256, 0, stream>>>(A, wl + 393216, 256, 0, 64, 128, 192,
                                                        mlp_b1 + l * 512, nullptr, B, 1);    // tA
        gemm_mfma_k<4, false><<<2048, 256, 0, stream>>>(B, wl + 524288, 512, 0, 64, 128, 192,
                                                        mlp_b2 + l * 256, A, C, 2);          // partial
        gemm_mfma_k<4, false><<<2048, 256, 0, stream>>>(A, wl + 393216, 256, 256, 320, 384, 448,
                                                        mlp_b1 + l * 512, nullptr, B, 1);    // tB
        gemm_mfma_k<4, true><<<2048, 256, 0, stream>>>(B, wl + 524288 + 256, 512, 0, 64, 128, 192,
                                                       nullptr, C, h, 2);                    // y3->h + stats
        affine_k<<<1, 256, 0, stream>>>(bn3_g + l * 256, bn3_b + l * 256, 2);
        apply_k<<<2048, 256, 0, stream>>>(h);
    }

    pool_k<<<N_GRAPHS_, 256, 0, stream>>>(h, pooled);
    head_k<<<N_GRAPHS_, 128, 0, stream>>>(pooled, head_w1, head_b1, head_w2, head_b2,
                                          head_w3, head_b3, (float*)d_out);
}